// Round 2
// baseline (1000.171 us; speedup 1.0000x reference)
//
#include <hip/hip_runtime.h>
#include <cstdint>
#include <cstddef>

#define HIDDIM 128
#define NGRAPH_MAX 512

// ---------------------------------------------------------------- degree histogram
__global__ void k_deg(const int* __restrict__ dst, int* __restrict__ deg, int E) {
    int i = blockIdx.x * 256 + threadIdx.x;
    if (i < E) atomicAdd(&deg[dst[i]], 1);
}

// ---------------------------------------------------------------- per-node stats: graph counts + max depth
__global__ void k_nodestats(const int* __restrict__ batch, const int* __restrict__ depth,
                            int* __restrict__ counts, int* __restrict__ maxd, int N, int G) {
    __shared__ int hist[NGRAPH_MAX];
    __shared__ int red[256];
    int t = threadIdx.x;
    for (int b = t; b < G; b += 256) hist[b] = 0;
    __syncthreads();
    int i = blockIdx.x * 256 + t;
    int d = 0;
    if (i < N) {
        atomicAdd(&hist[batch[i]], 1);
        d = depth[i];
    }
    red[t] = d;
    __syncthreads();
    for (int off = 128; off > 0; off >>= 1) {
        if (t < off) red[t] = max(red[t], red[t + off]);
        __syncthreads();
    }
    if (t == 0) atomicMax(maxd, red[0]);
    for (int b = t; b < G; b += 256)
        if (hist[b]) atomicAdd(&counts[b], hist[b]);
}

// ---------------------------------------------------------------- 3-phase exclusive scan (row_ptr)
__global__ void k_scan1(const int* __restrict__ deg, int* __restrict__ rp,
                        int* __restrict__ bsums, int N) {
    __shared__ int sd[256];
    int t = threadIdx.x;
    int base = blockIdx.x * 1024 + t * 4;
    int v0 = 0, v1 = 0, v2 = 0, v3 = 0;
    if (base + 0 < N) v0 = deg[base + 0];
    if (base + 1 < N) v1 = deg[base + 1];
    if (base + 2 < N) v2 = deg[base + 2];
    if (base + 3 < N) v3 = deg[base + 3];
    int ts = v0 + v1 + v2 + v3;
    sd[t] = ts;
    __syncthreads();
    for (int off = 1; off < 256; off <<= 1) {
        int x = (t >= off) ? sd[t - off] : 0;
        __syncthreads();
        sd[t] += x;
        __syncthreads();
    }
    int excl = sd[t] - ts;
    if (base + 0 < N) rp[base + 0] = excl;
    if (base + 1 < N) rp[base + 1] = excl + v0;
    if (base + 2 < N) rp[base + 2] = excl + v0 + v1;
    if (base + 3 < N) rp[base + 3] = excl + v0 + v1 + v2;
    if (t == 255) bsums[blockIdx.x] = sd[255];
}

__global__ void k_scan2(int* __restrict__ bsums, int nb) {
    __shared__ int sd[256];
    int t = threadIdx.x;
    int v = (t < nb) ? bsums[t] : 0;
    sd[t] = v;
    __syncthreads();
    for (int off = 1; off < 256; off <<= 1) {
        int x = (t >= off) ? sd[t - off] : 0;
        __syncthreads();
        sd[t] += x;
        __syncthreads();
    }
    if (t < nb) bsums[t] = sd[t] - v;
}

__global__ void k_scan3(int* __restrict__ rp, const int* __restrict__ bsums, int N, int E) {
    int t = threadIdx.x;
    int add = bsums[blockIdx.x];
    int base = blockIdx.x * 1024 + t * 4;
    #pragma unroll
    for (int j = 0; j < 4; j++)
        if (base + j < N) rp[base + j] += add;
    if (blockIdx.x == 0 && t == 0) rp[N] = E;
}

__global__ void k_invdeg(const int* __restrict__ deg, float* __restrict__ invd, int N) {
    int i = blockIdx.x * 256 + threadIdx.x;
    if (i < N) invd[i] = 1.0f / (float)max(deg[i], 1);
}

// ---------------------------------------------------------------- CSR fill (bucket edges by dst)
__global__ void k_fill(const int* __restrict__ src, const int* __restrict__ dst,
                       const int* __restrict__ rp, int* __restrict__ cursor,
                       int* __restrict__ srcs, int E) {
    int i = blockIdx.x * 256 + threadIdx.x;
    if (i < E) {
        int d = dst[i];
        int p = atomicAdd(&cursor[d], 1);
        srcs[rp[d] + p] = src[i];
    }
}

// ---------------------------------------------------------------- build node features [N,128] (cols 102..127 = 0)
__global__ void k_feat(const int* __restrict__ nt, const int* __restrict__ ih,
                       const float* __restrict__ flags, const int* __restrict__ depth,
                       const float* __restrict__ embN, const float* __restrict__ embI,
                       const int* __restrict__ maxd, float* __restrict__ x0, int N) {
    int idx = blockIdx.x * 256 + threadIdx.x;
    int i = idx >> 7;
    int f = idx & 127;
    if (i >= N) return;
    float v;
    if (f < 64)       v = embN[nt[i] * 64 + f];
    else if (f < 96)  v = embI[ih[i] * 32 + (f - 64)];
    else if (f < 101) v = flags[i * 5 + (f - 96)];
    else if (f == 101) {
        float md = fmaxf((float)(*maxd), 1.0f);
        v = (float)depth[i] / md;
    } else v = 0.0f;
    x0[(size_t)i * HIDDIM + f] = v;
}

// ---------------------------------------------------------------- fp32 GEMM: out[N,128] = X[N,K(<=128,stride128)] @ W[K,128]
// COMBINE==1: out = relu(X@W + bias_s + bias_n + Z)   (Z already deg-normalized)
// 128x128 tile/block, 512 threads, 4x8 register tile. X staged transposed in
// 64KB LDS (float4 a-loads: banks {0,4,8,12} + 16-way broadcast -> conflict
// free). W read from global (64KB, L1/L2 resident) so LDS<=64KB -> 2 blocks/CU.
template <int COMBINE>
__global__ __launch_bounds__(512, 4) void k_gemm(
    const float* __restrict__ X, const float* __restrict__ W, int K, int N,
    const float* __restrict__ bias_s, const float* __restrict__ bias_n,
    const float* __restrict__ Z,
    float* __restrict__ out) {
    __shared__ float Xt[128 * 128];  // [k][row], 64KB
    int t = threadIdx.x;
    int rowBase = blockIdx.x << 7;
    {
        int r = t >> 2;
        int gr = rowBase + r;
        int cb = (t & 3) << 5;
        const float* Xr = X + (size_t)gr * HIDDIM;
        #pragma unroll
        for (int j = 0; j < 8; j++) {
            int c = cb + (j << 2);
            float4 v = make_float4(0.f, 0.f, 0.f, 0.f);
            if (gr < N) v = *(const float4*)(Xr + c);
            Xt[(c + 0) * 128 + r] = v.x;
            Xt[(c + 1) * 128 + r] = v.y;
            Xt[(c + 2) * 128 + r] = v.z;
            Xt[(c + 3) * 128 + r] = v.w;
        }
    }
    __syncthreads();

    int r0 = (t >> 4) << 2;   // 32 row-groups * 4 rows
    int c0 = (t & 15) << 3;   // 16 col-groups * 8 cols
    float acc[4][8];
    #pragma unroll
    for (int i = 0; i < 4; i++)
        #pragma unroll
        for (int j = 0; j < 8; j++) acc[i][j] = 0.f;

    const float* Wp = W + c0;
    #pragma unroll 4
    for (int k = 0; k < K; k++) {
        float4 a  = *(const float4*)(Xt + (k << 7) + r0);
        float4 b0 = *(const float4*)(Wp);
        float4 b1 = *(const float4*)(Wp + 4);
        Wp += 128;
        float av[4] = {a.x, a.y, a.z, a.w};
        float bv[8] = {b0.x, b0.y, b0.z, b0.w, b1.x, b1.y, b1.z, b1.w};
        #pragma unroll
        for (int i = 0; i < 4; i++)
            #pragma unroll
            for (int j = 0; j < 8; j++)
                acc[i][j] = fmaf(av[i], bv[j], acc[i][j]);
    }

    #pragma unroll
    for (int i = 0; i < 4; i++) {
        int gr = rowBase + r0 + i;
        if (gr >= N) continue;
        float* orow = out + (size_t)gr * HIDDIM + c0;
        if (COMBINE) {
            const float* zrow = Z + (size_t)gr * HIDDIM + c0;
            float4 z0 = *(const float4*)(zrow);
            float4 z1 = *(const float4*)(zrow + 4);
            float4 s0 = *(const float4*)(bias_s + c0);
            float4 s1 = *(const float4*)(bias_s + c0 + 4);
            float4 n0 = *(const float4*)(bias_n + c0);
            float4 n1 = *(const float4*)(bias_n + c0 + 4);
            float4 o0, o1;
            o0.x = fmaxf(acc[i][0] + s0.x + n0.x + z0.x, 0.f);
            o0.y = fmaxf(acc[i][1] + s0.y + n0.y + z0.y, 0.f);
            o0.z = fmaxf(acc[i][2] + s0.z + n0.z + z0.z, 0.f);
            o0.w = fmaxf(acc[i][3] + s0.w + n0.w + z0.w, 0.f);
            o1.x = fmaxf(acc[i][4] + s1.x + n1.x + z1.x, 0.f);
            o1.y = fmaxf(acc[i][5] + s1.y + n1.y + z1.y, 0.f);
            o1.z = fmaxf(acc[i][6] + s1.z + n1.z + z1.z, 0.f);
            o1.w = fmaxf(acc[i][7] + s1.w + n1.w + z1.w, 0.f);
            *(float4*)(orow)     = o0;
            *(float4*)(orow + 4) = o1;
        } else {
            *(float4*)(orow)     = make_float4(acc[i][0], acc[i][1], acc[i][2], acc[i][3]);
            *(float4*)(orow + 4) = make_float4(acc[i][4], acc[i][5], acc[i][6], acc[i][7]);
        }
    }
}

// ---------------------------------------------------------------- CSR gather-aggregate: z[d] = invd[d] * sum_{e in in(d)} y[src[e]]
__global__ void k_agg(const float* __restrict__ y, const int* __restrict__ rp,
                      const int* __restrict__ srcs, const float* __restrict__ invd,
                      float* __restrict__ z) {
    __shared__ int sl[128];
    int d = blockIdx.x;
    int t = threadIdx.x;
    int s = rp[d], e = rp[d + 1];
    float acc = 0.f;
    for (int base = s; base < e; base += 128) {
        int m = min(128, e - base);
        if (t < m) sl[t] = srcs[base + t];
        __syncthreads();
        for (int i = 0; i < m; i++)
            acc += y[(size_t)sl[i] * HIDDIM + t];
        __syncthreads();
    }
    z[(size_t)d * HIDDIM + t] = acc * invd[d];
}

// ---------------------------------------------------------------- graph-start offsets (counts scan, G<=512)
__global__ void k_scang(const int* __restrict__ counts, int* __restrict__ gstart, int G) {
    __shared__ int sd[NGRAPH_MAX];
    int t = threadIdx.x;  // blockDim = 512
    int v = (t < G) ? counts[t] : 0;
    sd[t] = v;
    __syncthreads();
    for (int off = 1; off < 512; off <<= 1) {
        int x = (t >= off) ? sd[t - off] : 0;
        __syncthreads();
        sd[t] += x;
        __syncthreads();
    }
    if (t < G) gstart[t] = sd[t] - v;
    if (t == G - 1) gstart[G] = sd[t];
}

// ---------------------------------------------------------------- mean pool (sorted batch -> contiguous row ranges)
__global__ void k_pool(const float* __restrict__ x, const int* __restrict__ gstart,
                       const int* __restrict__ counts, float* __restrict__ g) {
    int gr = blockIdx.x;
    int t = threadIdx.x;
    int s = gstart[gr], e = gstart[gr + 1];
    float acc = 0.f;
    for (int i = s; i < e; i++)
        acc += x[(size_t)i * HIDDIM + t];
    g[(size_t)gr * HIDDIM + t] = acc / fmaxf((float)counts[gr], 1.f);
}

// ---------------------------------------------------------------- output heads
__global__ void k_head(const float* __restrict__ g, const float* __restrict__ Wr,
                       const float* __restrict__ br, const float* __restrict__ Wc,
                       const float* __restrict__ bc, float* __restrict__ out, int G) {
    __shared__ float row[128];
    int gr = blockIdx.x;
    int t = threadIdx.x;
    row[t] = g[(size_t)gr * HIDDIM + t];
    __syncthreads();
    if (t == 0) {
        float s = 0.f;
        for (int k = 0; k < 128; k++) s += row[k] * Wr[k];
        out[gr] = s + br[0];
    } else if (t <= 10) {
        int j = t - 1;
        float s = 0.f;
        for (int k = 0; k < 128; k++) s += row[k] * Wc[k * 10 + j];
        out[G + gr * 10 + j] = s + bc[j];
    }
}

// ================================================================ host
extern "C" void kernel_launch(void* const* d_in, const int* in_sizes, int n_in,
                              void* d_out, int out_size, void* d_ws, size_t ws_size,
                              hipStream_t stream) {
    const int*   nt    = (const int*)d_in[0];
    const int*   ih    = (const int*)d_in[1];
    const float* flags = (const float*)d_in[2];
    const int*   depth = (const int*)d_in[3];
    const int*   eidx  = (const int*)d_in[4];
    const int*   batch = (const int*)d_in[5];
    const float* embN  = (const float*)d_in[6];
    const float* embI  = (const float*)d_in[7];
    const float* Ws0   = (const float*)d_in[8];
    const float* bs0   = (const float*)d_in[9];
    const float* Wn0   = (const float*)d_in[10];
    const float* bn0   = (const float*)d_in[11];
    const float* Ws1   = (const float*)d_in[12];
    const float* bs1   = (const float*)d_in[13];
    const float* Wn1   = (const float*)d_in[14];
    const float* bn1   = (const float*)d_in[15];
    const float* Wr    = (const float*)d_in[16];
    const float* br    = (const float*)d_in[17];
    const float* Wc    = (const float*)d_in[18];
    const float* bc    = (const float*)d_in[19];
    float* out = (float*)d_out;

    const int N  = in_sizes[0];
    const int E  = in_sizes[4] / 2;
    const int K0 = in_sizes[8] / HIDDIM;   // 102
    const int G  = out_size / 11;          // 512
    const int* esrc = eidx;
    const int* edst = eidx + E;

    // ---- workspace carve-up
    char* w = (char*)d_ws;
    const size_t NB = (size_t)N * HIDDIM * sizeof(float);
    float* x0   = (float*)(w);            // N x 128
    float* bufY = (float*)(w + NB);       // N x 128
    float* bufZ = (float*)(w + 2 * NB);   // N x 128
    float* bufX1= (float*)(w + 3 * NB);   // N x 128
    char* p = w + 4 * NB;
    int* deg    = (int*)p;           p += (size_t)N * 4;
    int* cursor = (int*)p;           p += (size_t)N * 4;
    int* counts = (int*)p;           p += (size_t)G * 4;
    int* maxd   = (int*)p;           p += 4;
    // everything from deg..maxd zeroed in one memset:
    const size_t zero_bytes = (size_t)(2 * N + G + 1) * 4;
    int* rowptr = (int*)p;           p += (size_t)(N + 1) * 4;
    int* bsums  = (int*)p;           p += 256 * 4;
    int* gstart = (int*)p;           p += (size_t)(G + 1) * 4;
    float* invd = (float*)p;         p += (size_t)N * 4;
    int* srcs   = (int*)p;           p += (size_t)E * 4;
    float* gmat = (float*)p;         p += (size_t)G * HIDDIM * 4;
    (void)n_in; (void)ws_size;

    const int nbN   = (N + 255) / 256;
    const int nbE   = (E + 255) / 256;
    const int nbS   = (N + 1023) / 1024;       // scan blocks (<=256)
    const int nbF   = ((size_t)N * HIDDIM + 255) / 256;
    const int nbG   = (N + 127) / 128;         // gemm row tiles

    hipMemsetAsync(deg, 0, zero_bytes, stream);

    // graph structure
    k_deg<<<nbE, 256, 0, stream>>>(edst, deg, E);
    k_nodestats<<<nbN, 256, 0, stream>>>(batch, depth, counts, maxd, N, G);
    k_scan1<<<nbS, 256, 0, stream>>>(deg, rowptr, bsums, N);
    k_scan2<<<1, 256, 0, stream>>>(bsums, nbS);
    k_scan3<<<nbS, 256, 0, stream>>>(rowptr, bsums, N, E);
    k_invdeg<<<nbN, 256, 0, stream>>>(deg, invd, N);
    k_fill<<<nbE, 256, 0, stream>>>(esrc, edst, rowptr, cursor, srcs, E);

    // node features
    k_feat<<<nbF, 256, 0, stream>>>(nt, ih, flags, depth, embN, embI, maxd, x0, N);

    // layer 0: y = x0 @ Wn0 ; z = invd * A y ; x1 = relu(x0@Ws0 + bs0 + bn0 + z)
    k_gemm<0><<<nbG, 512, 0, stream>>>(x0, Wn0, K0, N, nullptr, nullptr, nullptr, bufY);
    k_agg<<<N, 128, 0, stream>>>(bufY, rowptr, srcs, invd, bufZ);
    k_gemm<1><<<nbG, 512, 0, stream>>>(x0, Ws0, K0, N, bs0, bn0, bufZ, bufX1);

    // layer 1: y1 = x1 @ Wn1 (into x0 buf) ; z = invd * A y1 ; x2 = relu(...) (into bufY)
    k_gemm<0><<<nbG, 512, 0, stream>>>(bufX1, Wn1, HIDDIM, N, nullptr, nullptr, nullptr, x0);
    k_agg<<<N, 128, 0, stream>>>(x0, rowptr, srcs, invd, bufZ);
    k_gemm<1><<<nbG, 512, 0, stream>>>(bufX1, Ws1, HIDDIM, N, bs1, bn1, bufZ, bufY);

    // pool + heads
    k_scang<<<1, 512, 0, stream>>>(counts, gstart, G);
    k_pool<<<G, 128, 0, stream>>>(bufY, gstart, counts, gmat);
    k_head<<<G, 128, 0, stream>>>(gmat, Wr, br, Wc, bc, out, G);
}

// Round 3
// 701.518 us; speedup vs baseline: 1.4257x; 1.4257x over previous
//
#include <hip/hip_runtime.h>
#include <cstdint>
#include <cstddef>

#define HIDDIM 128
#define NGRAPH_MAX 512
#define LDSPAD 136   // 128 + 8 bf16 pad: row stride 272B (16B-aligned, breaks pow2 banks)

using short8 = __attribute__((ext_vector_type(8))) short;
using f32x4  = __attribute__((ext_vector_type(4))) float;

__device__ __forceinline__ unsigned short f2bf(float x) {
    union { float f; uint32_t u; } v; v.f = x;
    uint32_t r = v.u + 0x7fffu + ((v.u >> 16) & 1u);   // RNE
    return (unsigned short)(r >> 16);
}
__device__ __forceinline__ float bf2f(unsigned short h) {
    union { uint32_t u; float f; } v; v.u = ((uint32_t)h) << 16;
    return v.f;
}

// ---------------------------------------------------------------- degree histogram
__global__ void k_deg(const int* __restrict__ dst, int* __restrict__ deg, int E) {
    int i = blockIdx.x * 256 + threadIdx.x;
    if (i < E) atomicAdd(&deg[dst[i]], 1);
}

// ---------------------------------------------------------------- per-node stats: graph counts + max depth
__global__ void k_nodestats(const int* __restrict__ batch, const int* __restrict__ depth,
                            int* __restrict__ counts, int* __restrict__ maxd, int N, int G) {
    __shared__ int hist[NGRAPH_MAX];
    __shared__ int red[256];
    int t = threadIdx.x;
    for (int b = t; b < G; b += 256) hist[b] = 0;
    __syncthreads();
    int i = blockIdx.x * 256 + t;
    int d = 0;
    if (i < N) {
        atomicAdd(&hist[batch[i]], 1);
        d = depth[i];
    }
    red[t] = d;
    __syncthreads();
    for (int off = 128; off > 0; off >>= 1) {
        if (t < off) red[t] = max(red[t], red[t + off]);
        __syncthreads();
    }
    if (t == 0) atomicMax(maxd, red[0]);
    for (int b = t; b < G; b += 256)
        if (hist[b]) atomicAdd(&counts[b], hist[b]);
}

// ---------------------------------------------------------------- 3-phase exclusive scan (row_ptr)
__global__ void k_scan1(const int* __restrict__ deg, int* __restrict__ rp,
                        int* __restrict__ bsums, int N) {
    __shared__ int sd[256];
    int t = threadIdx.x;
    int base = blockIdx.x * 1024 + t * 4;
    int v0 = 0, v1 = 0, v2 = 0, v3 = 0;
    if (base + 0 < N) v0 = deg[base + 0];
    if (base + 1 < N) v1 = deg[base + 1];
    if (base + 2 < N) v2 = deg[base + 2];
    if (base + 3 < N) v3 = deg[base + 3];
    int ts = v0 + v1 + v2 + v3;
    sd[t] = ts;
    __syncthreads();
    for (int off = 1; off < 256; off <<= 1) {
        int x = (t >= off) ? sd[t - off] : 0;
        __syncthreads();
        sd[t] += x;
        __syncthreads();
    }
    int excl = sd[t] - ts;
    if (base + 0 < N) rp[base + 0] = excl;
    if (base + 1 < N) rp[base + 1] = excl + v0;
    if (base + 2 < N) rp[base + 2] = excl + v0 + v1;
    if (base + 3 < N) rp[base + 3] = excl + v0 + v1 + v2;
    if (t == 255) bsums[blockIdx.x] = sd[255];
}

__global__ void k_scan2(int* __restrict__ bsums, int nb) {
    __shared__ int sd[256];
    int t = threadIdx.x;
    int v = (t < nb) ? bsums[t] : 0;
    sd[t] = v;
    __syncthreads();
    for (int off = 1; off < 256; off <<= 1) {
        int x = (t >= off) ? sd[t - off] : 0;
        __syncthreads();
        sd[t] += x;
        __syncthreads();
    }
    if (t < nb) bsums[t] = sd[t] - v;
}

__global__ void k_scan3(int* __restrict__ rp, const int* __restrict__ bsums, int N, int E) {
    int t = threadIdx.x;
    int add = bsums[blockIdx.x];
    int base = blockIdx.x * 1024 + t * 4;
    #pragma unroll
    for (int j = 0; j < 4; j++)
        if (base + j < N) rp[base + j] += add;
    if (blockIdx.x == 0 && t == 0) rp[N] = E;
}

// invd + cursor init (cursor = rowptr so k_fill needs no rp read)
__global__ void k_invdeg(const int* __restrict__ deg, const int* __restrict__ rp,
                         float* __restrict__ invd, int* __restrict__ cursor, int N) {
    int i = blockIdx.x * 256 + threadIdx.x;
    if (i < N) {
        invd[i] = 1.0f / (float)max(deg[i], 1);
        cursor[i] = rp[i];
    }
}

// ---------------------------------------------------------------- CSR fill (bucket edges by dst)
__global__ void k_fill(const int* __restrict__ src, const int* __restrict__ dst,
                       int* __restrict__ cursor, int* __restrict__ srcs, int E) {
    int i = blockIdx.x * 256 + threadIdx.x;
    if (i < E) {
        int p = atomicAdd(&cursor[dst[i]], 1);
        srcs[p] = src[i];
    }
}

// ---------------------------------------------------------------- node features [N,128] bf16 (cols 102..127 = 0)
__global__ void k_feat(const int* __restrict__ nt, const int* __restrict__ ih,
                       const float* __restrict__ flags, const int* __restrict__ depth,
                       const float* __restrict__ embN, const float* __restrict__ embI,
                       const int* __restrict__ maxd, unsigned short* __restrict__ x0, int N) {
    int idx = blockIdx.x * 256 + threadIdx.x;
    int i = idx >> 7;
    int f = idx & 127;
    if (i >= N) return;
    float v;
    if (f < 64)       v = embN[nt[i] * 64 + f];
    else if (f < 96)  v = embI[ih[i] * 32 + (f - 64)];
    else if (f < 101) v = flags[i * 5 + (f - 96)];
    else if (f == 101) {
        float md = fmaxf((float)(*maxd), 1.0f);
        v = (float)depth[i] / md;
    } else v = 0.0f;
    x0[(size_t)i * HIDDIM + f] = f2bf(v);
}

// ---------------------------------------------------------------- bf16 MFMA GEMM
// out[N,128](bf16) = X[N,K<=128, bf16 stride 128] @ W[K,128](fp32->bf16)
// COMBINE: out = relu(X@W + bias_s + bias_n + Z)     (Z fp32, deg-normalized)
// 128x128 tile/block, 256 thr (4 waves), no K-loop (K<=128 in LDS).
// Frags (m89-verified): A[m=lane&15][k=quad*8+j]; B^T in LDS Bt[n][k];
// C/D col=lane&15, row=quad*4+reg.
template <int COMBINE>
__global__ __launch_bounds__(256, 2) void k_gemm(
    const unsigned short* __restrict__ X, const float* __restrict__ W, int K, int N,
    const float* __restrict__ bias_s, const float* __restrict__ bias_n,
    const float* __restrict__ Z,
    unsigned short* __restrict__ out) {
    __shared__ unsigned short As[128 * LDSPAD];  // [row][k]
    __shared__ unsigned short Bs[128 * LDSPAD];  // [n][k]
    int t = threadIdx.x;
    int rowBase = blockIdx.x << 7;

    // stage A: 128 rows x 16 chunks of 16B
    #pragma unroll
    for (int it = 0; it < 8; it++) {
        int idx = t + it * 256;
        int r = idx >> 4, seg = idx & 15;
        int gr = rowBase + r;
        uint4 v = make_uint4(0u, 0u, 0u, 0u);
        if (gr < N) v = *(const uint4*)(X + (size_t)gr * HIDDIM + seg * 8);
        *(uint4*)&As[r * LDSPAD + seg * 8] = v;
    }
    // stage B transposed + cvt; zero-pad k in [K,128)
    #pragma unroll
    for (int it = 0; it < 16; it++) {
        int idx = t + it * 256;          // 4096 float4-chunks
        int k = idx >> 5, n4 = (idx & 31) << 2;
        float4 v = make_float4(0.f, 0.f, 0.f, 0.f);
        if (k < K) v = *(const float4*)(W + (size_t)k * HIDDIM + n4);
        Bs[(n4 + 0) * LDSPAD + k] = f2bf(v.x);
        Bs[(n4 + 1) * LDSPAD + k] = f2bf(v.y);
        Bs[(n4 + 2) * LDSPAD + k] = f2bf(v.z);
        Bs[(n4 + 3) * LDSPAD + k] = f2bf(v.w);
    }
    __syncthreads();

    int lane = t & 63;
    int wv = t >> 6;          // wave 0..3 -> rows [wv*32, wv*32+32)
    int ml = lane & 15;
    int quad = lane >> 4;
    int m0 = wv * 32;

    f32x4 acc[2][8];
    #pragma unroll
    for (int i = 0; i < 2; i++)
        #pragma unroll
        for (int j = 0; j < 8; j++) acc[i][j] = (f32x4){0.f, 0.f, 0.f, 0.f};

    #pragma unroll
    for (int kt = 0; kt < 4; kt++) {
        int ko = kt * 32 + quad * 8;
        short8 a0 = *(const short8*)&As[(m0 + ml) * LDSPAD + ko];
        short8 a1 = *(const short8*)&As[(m0 + 16 + ml) * LDSPAD + ko];
        #pragma unroll
        for (int nt = 0; nt < 8; nt++) {
            short8 b = *(const short8*)&Bs[(nt * 16 + ml) * LDSPAD + ko];
            acc[0][nt] = __builtin_amdgcn_mfma_f32_16x16x32_bf16(a0, b, acc[0][nt], 0, 0, 0);
            acc[1][nt] = __builtin_amdgcn_mfma_f32_16x16x32_bf16(a1, b, acc[1][nt], 0, 0, 0);
        }
    }

    float bsum[8];
    if (COMBINE) {
        #pragma unroll
        for (int nt = 0; nt < 8; nt++) {
            int col = nt * 16 + ml;
            bsum[nt] = bias_s[col] + bias_n[col];
        }
    }

    #pragma unroll
    for (int mt = 0; mt < 2; mt++) {
        int grow0 = rowBase + m0 + mt * 16 + quad * 4;
        #pragma unroll
        for (int r = 0; r < 4; r++) {
            int grow = grow0 + r;
            if (grow >= N) continue;
            #pragma unroll
            for (int nt = 0; nt < 8; nt++) {
                int col = nt * 16 + ml;
                float v = acc[mt][nt][r];
                if (COMBINE)
                    v = fmaxf(v + bsum[nt] + Z[(size_t)grow * HIDDIM + col], 0.f);
                out[(size_t)grow * HIDDIM + col] = f2bf(v);
            }
        }
    }
}

// ---------------------------------------------------------------- CSR gather-aggregate (bf16 rows, fp32 acc)
__global__ void k_agg(const unsigned short* __restrict__ y, const int* __restrict__ rp,
                      const int* __restrict__ srcs, const float* __restrict__ invd,
                      float* __restrict__ z) {
    __shared__ int sl[128];
    int d = blockIdx.x;
    int t = threadIdx.x;
    int s = rp[d], e = rp[d + 1];
    float acc = 0.f;
    for (int base = s; base < e; base += 128) {
        int m = min(128, e - base);
        if (t < m) sl[t] = srcs[base + t];
        __syncthreads();
        for (int i = 0; i < m; i++)
            acc += bf2f(y[(size_t)sl[i] * HIDDIM + t]);
        __syncthreads();
    }
    z[(size_t)d * HIDDIM + t] = acc * invd[d];
}

// ---------------------------------------------------------------- graph-start offsets (counts scan, G<=512)
__global__ void k_scang(const int* __restrict__ counts, int* __restrict__ gstart, int G) {
    __shared__ int sd[NGRAPH_MAX];
    int t = threadIdx.x;  // blockDim = 512
    int v = (t < G) ? counts[t] : 0;
    sd[t] = v;
    __syncthreads();
    for (int off = 1; off < 512; off <<= 1) {
        int x = (t >= off) ? sd[t - off] : 0;
        __syncthreads();
        sd[t] += x;
        __syncthreads();
    }
    if (t < G) gstart[t] = sd[t] - v;
    if (t == G - 1) gstart[G] = sd[t];
}

// ---------------------------------------------------------------- mean pool (sorted batch -> contiguous row ranges)
__global__ void k_pool(const unsigned short* __restrict__ x, const int* __restrict__ gstart,
                       const int* __restrict__ counts, float* __restrict__ g) {
    int gr = blockIdx.x;
    int t = threadIdx.x;
    int s = gstart[gr], e = gstart[gr + 1];
    float acc = 0.f;
    for (int i = s; i < e; i++)
        acc += bf2f(x[(size_t)i * HIDDIM + t]);
    g[(size_t)gr * HIDDIM + t] = acc / fmaxf((float)counts[gr], 1.f);
}

// ---------------------------------------------------------------- output heads
__global__ void k_head(const float* __restrict__ g, const float* __restrict__ Wr,
                       const float* __restrict__ br, const float* __restrict__ Wc,
                       const float* __restrict__ bc, float* __restrict__ out, int G) {
    __shared__ float row[128];
    int gr = blockIdx.x;
    int t = threadIdx.x;
    row[t] = g[(size_t)gr * HIDDIM + t];
    __syncthreads();
    if (t == 0) {
        float s = 0.f;
        for (int k = 0; k < 128; k++) s += row[k] * Wr[k];
        out[gr] = s + br[0];
    } else if (t <= 10) {
        int j = t - 1;
        float s = 0.f;
        for (int k = 0; k < 128; k++) s += row[k] * Wc[k * 10 + j];
        out[G + gr * 10 + j] = s + bc[j];
    }
}

// ================================================================ host
extern "C" void kernel_launch(void* const* d_in, const int* in_sizes, int n_in,
                              void* d_out, int out_size, void* d_ws, size_t ws_size,
                              hipStream_t stream) {
    const int*   nt    = (const int*)d_in[0];
    const int*   ih    = (const int*)d_in[1];
    const float* flags = (const float*)d_in[2];
    const int*   depth = (const int*)d_in[3];
    const int*   eidx  = (const int*)d_in[4];
    const int*   batch = (const int*)d_in[5];
    const float* embN  = (const float*)d_in[6];
    const float* embI  = (const float*)d_in[7];
    const float* Ws0   = (const float*)d_in[8];
    const float* bs0   = (const float*)d_in[9];
    const float* Wn0   = (const float*)d_in[10];
    const float* bn0   = (const float*)d_in[11];
    const float* Ws1   = (const float*)d_in[12];
    const float* bs1   = (const float*)d_in[13];
    const float* Wn1   = (const float*)d_in[14];
    const float* bn1   = (const float*)d_in[15];
    const float* Wr    = (const float*)d_in[16];
    const float* br    = (const float*)d_in[17];
    const float* Wc    = (const float*)d_in[18];
    const float* bc    = (const float*)d_in[19];
    float* out = (float*)d_out;

    const int N  = in_sizes[0];
    const int E  = in_sizes[4] / 2;
    const int K0 = in_sizes[8] / HIDDIM;   // 102
    const int G  = out_size / 11;          // 512
    const int* esrc = eidx;
    const int* edst = eidx + E;

    // ---- workspace carve-up
    char* w = (char*)d_ws;
    const size_t NZ = (size_t)N * HIDDIM * sizeof(float);      // fp32 N x 128
    const size_t NH = (size_t)N * HIDDIM * sizeof(unsigned short); // bf16 N x 128
    float*          bufZ  = (float*)(w);                // N x 128 fp32
    unsigned short* x0    = (unsigned short*)(w + NZ);          // bf16
    unsigned short* bufY  = (unsigned short*)(w + NZ + NH);     // bf16
    unsigned short* bufX1 = (unsigned short*)(w + NZ + 2 * NH); // bf16
    char* p = w + NZ + 3 * NH;
    int* deg    = (int*)p;           p += (size_t)N * 4;
    int* cursor = (int*)p;           p += (size_t)N * 4;
    int* counts = (int*)p;           p += (size_t)G * 4;
    int* maxd   = (int*)p;           p += 4;
    // deg..maxd zeroed in one memset:
    const size_t zero_bytes = (size_t)(2 * N + G + 1) * 4;
    int* rowptr = (int*)p;           p += (size_t)(N + 1) * 4;
    int* bsums  = (int*)p;           p += 256 * 4;
    int* gstart = (int*)p;           p += (size_t)(G + 1) * 4;
    float* invd = (float*)p;         p += (size_t)N * 4;
    int* srcs   = (int*)p;           p += (size_t)E * 4;
    float* gmat = (float*)p;         p += (size_t)G * HIDDIM * 4;
    (void)n_in; (void)ws_size;

    const int nbN = (N + 255) / 256;
    const int nbE = (E + 255) / 256;
    const int nbS = (N + 1023) / 1024;
    const int nbF = ((size_t)N * HIDDIM + 255) / 256;
    const int nbG = (N + 127) / 128;

    hipMemsetAsync(deg, 0, zero_bytes, stream);

    // graph structure
    k_deg<<<nbE, 256, 0, stream>>>(edst, deg, E);
    k_nodestats<<<nbN, 256, 0, stream>>>(batch, depth, counts, maxd, N, G);
    k_scan1<<<nbS, 256, 0, stream>>>(deg, rowptr, bsums, N);
    k_scan2<<<1, 256, 0, stream>>>(bsums, nbS);
    k_scan3<<<nbS, 256, 0, stream>>>(rowptr, bsums, N, E);
    k_invdeg<<<nbN, 256, 0, stream>>>(deg, rowptr, invd, cursor, N);
    k_fill<<<nbE, 256, 0, stream>>>(esrc, edst, cursor, srcs, E);

    // node features (bf16)
    k_feat<<<nbF, 256, 0, stream>>>(nt, ih, flags, depth, embN, embI, maxd, x0, N);

    // layer 0
    k_gemm<0><<<nbG, 256, 0, stream>>>(x0, Wn0, K0, N, nullptr, nullptr, nullptr, bufY);
    k_agg<<<N, 128, 0, stream>>>(bufY, rowptr, srcs, invd, bufZ);
    k_gemm<1><<<nbG, 256, 0, stream>>>(x0, Ws0, K0, N, bs0, bn0, bufZ, bufX1);

    // layer 1
    k_gemm<0><<<nbG, 256, 0, stream>>>(bufX1, Wn1, HIDDIM, N, nullptr, nullptr, nullptr, bufY);
    k_agg<<<N, 128, 0, stream>>>(bufY, rowptr, srcs, invd, bufZ);
    k_gemm<1><<<nbG, 256, 0, stream>>>(bufX1, Ws1, HIDDIM, N, bs1, bn1, bufZ, bufY);

    // pool + heads
    k_scang<<<1, 512, 0, stream>>>(counts, gstart, G);
    k_pool<<<G, 128, 0, stream>>>(bufY, gstart, counts, gmat);
    k_head<<<G, 128, 0, stream>>>(gmat, Wr, br, Wc, bc, out, G);
}

// Round 4
// 616.797 us; speedup vs baseline: 1.6216x; 1.1374x over previous
//
#include <hip/hip_runtime.h>
#include <cstdint>
#include <cstddef>

#define HIDDIM 128
#define NGRAPH_MAX 512
#define LDSPAD 136   // 128 + 8 bf16 pad: row stride 272B (16B-aligned, breaks pow2 banks)
#define NBKT_MAX 512 // coarse buckets of 256 nodes (dst>>8); N<=131072

using short8 = __attribute__((ext_vector_type(8))) short;
using f32x4  = __attribute__((ext_vector_type(4))) float;

__device__ __forceinline__ unsigned short f2bf(float x) {
    union { float f; uint32_t u; } v; v.f = x;
    uint32_t r = v.u + 0x7fffu + ((v.u >> 16) & 1u);   // RNE
    return (unsigned short)(r >> 16);
}
__device__ __forceinline__ float bf2f(unsigned short h) {
    union { uint32_t u; float f; } v; v.u = ((uint32_t)h) << 16;
    return v.f;
}

// ---------------------------------------------------------------- bucket histogram (dst>>8), LDS-aggregated
__global__ void k_bcount(const int* __restrict__ dst, int* __restrict__ bcount, int E) {
    __shared__ int hist[NBKT_MAX];
    int t = threadIdx.x;
    hist[t] = 0; hist[t + 256] = 0;
    __syncthreads();
    int c0 = blockIdx.x * 4096;
    int ce = min(4096, E - c0);
    for (int i = t; i < ce; i += 256)
        atomicAdd(&hist[dst[c0 + i] >> 8], 1);
    __syncthreads();
    for (int b = t; b < NBKT_MAX; b += 256)
        if (hist[b]) atomicAdd(&bcount[b], hist[b]);
}

// ---------------------------------------------------------------- bucket offsets (single block, 512 thr)
__global__ void k_bscan(const int* __restrict__ bcount, int* __restrict__ boff,
                        int* __restrict__ bcur, int* __restrict__ rowptr,
                        int nbkt, int N, int E) {
    __shared__ int sd[512];
    int t = threadIdx.x;
    int v = (t < nbkt) ? bcount[t] : 0;
    sd[t] = v;
    __syncthreads();
    for (int off = 1; off < 512; off <<= 1) {
        int x = (t >= off) ? sd[t - off] : 0;
        __syncthreads();
        sd[t] += x;
        __syncthreads();
    }
    if (t < nbkt) { boff[t] = sd[t] - v; bcur[t] = sd[t] - v; }
    if (t == 0) { boff[nbkt] = E; rowptr[N] = E; }
}

// ---------------------------------------------------------------- bucket scatter: LDS-sort 4096-edge chunk,
// per-(block,bucket) global reservation, coalesced run writes (XCD-local lines)
__global__ void k_bscatter(const int* __restrict__ src, const int* __restrict__ dst,
                           int* __restrict__ bcur, int2* __restrict__ ebuf, int E, int nbkt) {
    __shared__ int2 stage[4096];        // 32 KB
    __shared__ int hist[NBKT_MAX];
    __shared__ int ofs[NBKT_MAX];
    __shared__ int cur[NBKT_MAX];
    __shared__ int gbase[NBKT_MAX];
    __shared__ int scanbuf[256];
    int t = threadIdx.x;
    int c0 = blockIdx.x * 4096;
    int ce = min(4096, E - c0);

    hist[t] = 0; hist[t + 256] = 0;
    __syncthreads();
    for (int i = t; i < ce; i += 256)
        atomicAdd(&hist[dst[c0 + i] >> 8], 1);
    __syncthreads();
    // exclusive scan of hist[0..511] with 256 threads (pairwise)
    int h2a = hist[2 * t], h2b = hist[2 * t + 1];
    int ps = h2a + h2b;
    scanbuf[t] = ps;
    __syncthreads();
    for (int off = 1; off < 256; off <<= 1) {
        int x = (t >= off) ? scanbuf[t - off] : 0;
        __syncthreads();
        scanbuf[t] += x;
        __syncthreads();
    }
    int ex = scanbuf[t] - ps;
    ofs[2 * t] = ex;           cur[2 * t] = ex;
    ofs[2 * t + 1] = ex + h2a; cur[2 * t + 1] = ex + h2a;
    __syncthreads();
    // place chunk into stage, bucket-sorted
    for (int i = t; i < ce; i += 256) {
        int d = dst[c0 + i];
        int p = atomicAdd(&cur[d >> 8], 1);
        stage[p] = make_int2(src[c0 + i], d);
    }
    __syncthreads();
    // reserve contiguous global runs per bucket
    for (int b = t; b < nbkt; b += 256) {
        int c = hist[b];
        gbase[b] = c ? atomicAdd(&bcur[b], c) : 0;
    }
    __syncthreads();
    // flush: consecutive threads write consecutive addresses within each run
    for (int j = t; j < ce; j += 256) {
        int2 p = stage[j];
        int b = p.y >> 8;
        ebuf[gbase[b] + (j - ofs[b])] = p;
    }
}

// ---------------------------------------------------------------- per-bucket CSR build: deg, rowptr, invd, srcs
// one block per bucket; all writes land in a single-XCD 16KB window
__global__ void k_build(const int2* __restrict__ ebuf, const int* __restrict__ boff,
                        int* __restrict__ rowptr, float* __restrict__ invd,
                        int* __restrict__ srcs, int N) {
    __shared__ int ldeg[256];
    __shared__ int lofs[256];
    __shared__ int lcur[256];
    int b = blockIdx.x, t = threadIdx.x;
    int n0 = b << 8;
    int s = boff[b], e = boff[b + 1];
    ldeg[t] = 0;
    __syncthreads();
    for (int i = s + t; i < e; i += 256)
        atomicAdd(&ldeg[ebuf[i].y & 255], 1);
    __syncthreads();
    int v = ldeg[t];
    lofs[t] = v;
    __syncthreads();
    for (int off = 1; off < 256; off <<= 1) {
        int x = (t >= off) ? lofs[t - off] : 0;
        __syncthreads();
        lofs[t] += x;
        __syncthreads();
    }
    int excl = lofs[t] - v;
    int node = n0 + t;
    if (node < N) {
        rowptr[node] = s + excl;
        invd[node] = 1.0f / (float)max(v, 1);
    }
    lcur[t] = excl;
    __syncthreads();
    for (int i = s + t; i < e; i += 256) {
        int2 p = ebuf[i];
        int slot = atomicAdd(&lcur[p.y & 255], 1);
        srcs[s + slot] = p.x;
    }
}

// ---------------------------------------------------------------- per-node stats: graph counts + max depth
__global__ void k_nodestats(const int* __restrict__ batch, const int* __restrict__ depth,
                            int* __restrict__ counts, int* __restrict__ maxd, int N, int G) {
    __shared__ int hist[NGRAPH_MAX];
    __shared__ int red[256];
    int t = threadIdx.x;
    for (int b = t; b < G; b += 256) hist[b] = 0;
    __syncthreads();
    int i = blockIdx.x * 256 + t;
    int d = 0;
    if (i < N) {
        atomicAdd(&hist[batch[i]], 1);
        d = depth[i];
    }
    red[t] = d;
    __syncthreads();
    for (int off = 128; off > 0; off >>= 1) {
        if (t < off) red[t] = max(red[t], red[t + off]);
        __syncthreads();
    }
    if (t == 0) atomicMax(maxd, red[0]);
    for (int b = t; b < G; b += 256)
        if (hist[b]) atomicAdd(&counts[b], hist[b]);
}

// ---------------------------------------------------------------- node features [N,128] bf16 (cols 102..127 = 0)
__global__ void k_feat(const int* __restrict__ nt, const int* __restrict__ ih,
                       const float* __restrict__ flags, const int* __restrict__ depth,
                       const float* __restrict__ embN, const float* __restrict__ embI,
                       const int* __restrict__ maxd, unsigned short* __restrict__ x0, int N) {
    int idx = blockIdx.x * 256 + threadIdx.x;
    int i = idx >> 7;
    int f = idx & 127;
    if (i >= N) return;
    float v;
    if (f < 64)       v = embN[nt[i] * 64 + f];
    else if (f < 96)  v = embI[ih[i] * 32 + (f - 64)];
    else if (f < 101) v = flags[i * 5 + (f - 96)];
    else if (f == 101) {
        float md = fmaxf((float)(*maxd), 1.0f);
        v = (float)depth[i] / md;
    } else v = 0.0f;
    x0[(size_t)i * HIDDIM + f] = f2bf(v);
}

// ---------------------------------------------------------------- bf16 MFMA GEMM (unchanged from r3)
template <int COMBINE>
__global__ __launch_bounds__(256, 2) void k_gemm(
    const unsigned short* __restrict__ X, const float* __restrict__ W, int K, int N,
    const float* __restrict__ bias_s, const float* __restrict__ bias_n,
    const float* __restrict__ Z,
    unsigned short* __restrict__ out) {
    __shared__ unsigned short As[128 * LDSPAD];  // [row][k]
    __shared__ unsigned short Bs[128 * LDSPAD];  // [n][k]
    int t = threadIdx.x;
    int rowBase = blockIdx.x << 7;

    #pragma unroll
    for (int it = 0; it < 8; it++) {
        int idx = t + it * 256;
        int r = idx >> 4, seg = idx & 15;
        int gr = rowBase + r;
        uint4 v = make_uint4(0u, 0u, 0u, 0u);
        if (gr < N) v = *(const uint4*)(X + (size_t)gr * HIDDIM + seg * 8);
        *(uint4*)&As[r * LDSPAD + seg * 8] = v;
    }
    #pragma unroll
    for (int it = 0; it < 16; it++) {
        int idx = t + it * 256;
        int k = idx >> 5, n4 = (idx & 31) << 2;
        float4 v = make_float4(0.f, 0.f, 0.f, 0.f);
        if (k < K) v = *(const float4*)(W + (size_t)k * HIDDIM + n4);
        Bs[(n4 + 0) * LDSPAD + k] = f2bf(v.x);
        Bs[(n4 + 1) * LDSPAD + k] = f2bf(v.y);
        Bs[(n4 + 2) * LDSPAD + k] = f2bf(v.z);
        Bs[(n4 + 3) * LDSPAD + k] = f2bf(v.w);
    }
    __syncthreads();

    int lane = t & 63;
    int wv = t >> 6;
    int ml = lane & 15;
    int quad = lane >> 4;
    int m0 = wv * 32;

    f32x4 acc[2][8];
    #pragma unroll
    for (int i = 0; i < 2; i++)
        #pragma unroll
        for (int j = 0; j < 8; j++) acc[i][j] = (f32x4){0.f, 0.f, 0.f, 0.f};

    #pragma unroll
    for (int kt = 0; kt < 4; kt++) {
        int ko = kt * 32 + quad * 8;
        short8 a0 = *(const short8*)&As[(m0 + ml) * LDSPAD + ko];
        short8 a1 = *(const short8*)&As[(m0 + 16 + ml) * LDSPAD + ko];
        #pragma unroll
        for (int nt = 0; nt < 8; nt++) {
            short8 b = *(const short8*)&Bs[(nt * 16 + ml) * LDSPAD + ko];
            acc[0][nt] = __builtin_amdgcn_mfma_f32_16x16x32_bf16(a0, b, acc[0][nt], 0, 0, 0);
            acc[1][nt] = __builtin_amdgcn_mfma_f32_16x16x32_bf16(a1, b, acc[1][nt], 0, 0, 0);
        }
    }

    float bsum[8];
    if (COMBINE) {
        #pragma unroll
        for (int nt = 0; nt < 8; nt++) {
            int col = nt * 16 + ml;
            bsum[nt] = bias_s[col] + bias_n[col];
        }
    }

    #pragma unroll
    for (int mt = 0; mt < 2; mt++) {
        int grow0 = rowBase + m0 + mt * 16 + quad * 4;
        #pragma unroll
        for (int r = 0; r < 4; r++) {
            int grow = grow0 + r;
            if (grow >= N) continue;
            #pragma unroll
            for (int nt = 0; nt < 8; nt++) {
                int col = nt * 16 + ml;
                float v = acc[mt][nt][r];
                if (COMBINE)
                    v = fmaxf(v + bsum[nt] + Z[(size_t)grow * HIDDIM + col], 0.f);
                out[(size_t)grow * HIDDIM + col] = f2bf(v);
            }
        }
    }
}

// ---------------------------------------------------------------- CSR gather-aggregate: one WAVE per dst
// lane handles 2 cols via uint32 (2xbf16); srcs broadcast via shfl (no LDS, no barriers)
__global__ void k_agg(const uint32_t* __restrict__ y2, const int* __restrict__ rp,
                      const int* __restrict__ srcs, const float* __restrict__ invd,
                      float* __restrict__ z, int N) {
    int lane = threadIdx.x & 63;
    int d = blockIdx.x * 4 + (threadIdx.x >> 6);
    if (d >= N) return;
    int s = rp[d], e = rp[d + 1];
    float a0 = 0.f, a1 = 0.f;
    for (int base = s; base < e; base += 64) {
        int m = min(64, e - base);
        int idx = (lane < m) ? srcs[base + lane] : 0;
        for (int j = 0; j < m; j++) {
            int id = __shfl(idx, j, 64);
            uint32_t u = y2[(size_t)id * 64 + lane];
            a0 += __uint_as_float(u << 16);
            a1 += __uint_as_float(u & 0xffff0000u);
        }
    }
    float iv = invd[d];
    float2 o = make_float2(a0 * iv, a1 * iv);
    *(float2*)&z[(size_t)d * HIDDIM + 2 * lane] = o;
}

// ---------------------------------------------------------------- graph-start offsets (counts scan, G<=512)
__global__ void k_scang(const int* __restrict__ counts, int* __restrict__ gstart, int G) {
    __shared__ int sd[NGRAPH_MAX];
    int t = threadIdx.x;  // blockDim = 512
    int v = (t < G) ? counts[t] : 0;
    sd[t] = v;
    __syncthreads();
    for (int off = 1; off < 512; off <<= 1) {
        int x = (t >= off) ? sd[t - off] : 0;
        __syncthreads();
        sd[t] += x;
        __syncthreads();
    }
    if (t < G) gstart[t] = sd[t] - v;
    if (t == G - 1) gstart[G] = sd[t];
}

// ---------------------------------------------------------------- mean pool (sorted batch -> contiguous row ranges)
__global__ void k_pool(const unsigned short* __restrict__ x, const int* __restrict__ gstart,
                       const int* __restrict__ counts, float* __restrict__ g) {
    int gr = blockIdx.x;
    int t = threadIdx.x;
    int s = gstart[gr], e = gstart[gr + 1];
    float acc = 0.f;
    for (int i = s; i < e; i++)
        acc += bf2f(x[(size_t)i * HIDDIM + t]);
    g[(size_t)gr * HIDDIM + t] = acc / fmaxf((float)counts[gr], 1.f);
}

// ---------------------------------------------------------------- output heads
__global__ void k_head(const float* __restrict__ g, const float* __restrict__ Wr,
                       const float* __restrict__ br, const float* __restrict__ Wc,
                       const float* __restrict__ bc, float* __restrict__ out, int G) {
    __shared__ float row[128];
    int gr = blockIdx.x;
    int t = threadIdx.x;
    row[t] = g[(size_t)gr * HIDDIM + t];
    __syncthreads();
    if (t == 0) {
        float s = 0.f;
        for (int k = 0; k < 128; k++) s += row[k] * Wr[k];
        out[gr] = s + br[0];
    } else if (t <= 10) {
        int j = t - 1;
        float s = 0.f;
        for (int k = 0; k < 128; k++) s += row[k] * Wc[k * 10 + j];
        out[G + gr * 10 + j] = s + bc[j];
    }
}

// ================================================================ host
extern "C" void kernel_launch(void* const* d_in, const int* in_sizes, int n_in,
                              void* d_out, int out_size, void* d_ws, size_t ws_size,
                              hipStream_t stream) {
    const int*   nt    = (const int*)d_in[0];
    const int*   ih    = (const int*)d_in[1];
    const float* flags = (const float*)d_in[2];
    const int*   depth = (const int*)d_in[3];
    const int*   eidx  = (const int*)d_in[4];
    const int*   batch = (const int*)d_in[5];
    const float* embN  = (const float*)d_in[6];
    const float* embI  = (const float*)d_in[7];
    const float* Ws0   = (const float*)d_in[8];
    const float* bs0   = (const float*)d_in[9];
    const float* Wn0   = (const float*)d_in[10];
    const float* bn0   = (const float*)d_in[11];
    const float* Ws1   = (const float*)d_in[12];
    const float* bs1   = (const float*)d_in[13];
    const float* Wn1   = (const float*)d_in[14];
    const float* bn1   = (const float*)d_in[15];
    const float* Wr    = (const float*)d_in[16];
    const float* br    = (const float*)d_in[17];
    const float* Wc    = (const float*)d_in[18];
    const float* bc    = (const float*)d_in[19];
    float* out = (float*)d_out;

    const int N  = in_sizes[0];
    const int E  = in_sizes[4] / 2;
    const int K0 = in_sizes[8] / HIDDIM;   // 102
    const int G  = out_size / 11;          // 512
    const int* esrc = eidx;
    const int* edst = eidx + E;
    const int NBKT = (N + 255) >> 8;       // 391

    // ---- workspace carve-up
    char* w = (char*)d_ws;
    const size_t NZ = (size_t)N * HIDDIM * sizeof(float);
    const size_t NH = (size_t)N * HIDDIM * sizeof(unsigned short);
    float*          bufZ  = (float*)(w);
    unsigned short* x0    = (unsigned short*)(w + NZ);
    unsigned short* bufY  = (unsigned short*)(w + NZ + NH);
    unsigned short* bufX1 = (unsigned short*)(w + NZ + 2 * NH);
    char* p = w + NZ + 3 * NH;             // 8-byte aligned
    int2* ebuf  = (int2*)p;          p += (size_t)E * 8;
    int* srcs   = (int*)p;           p += (size_t)E * 4;
    int* rowptr = (int*)p;           p += (size_t)(N + 1) * 4;
    float* invd = (float*)p;         p += (size_t)N * 4;
    int* gstart = (int*)p;           p += (size_t)(G + 1) * 4;
    float* gmat = (float*)p;         p += (size_t)G * HIDDIM * 4;
    int* boff   = (int*)p;           p += (size_t)(NBKT_MAX + 1) * 4;
    int* bcur   = (int*)p;           p += (size_t)NBKT_MAX * 4;
    // zeroed block: bcount, counts, maxd (contiguous)
    int* bcount = (int*)p;           p += (size_t)NBKT_MAX * 4;
    int* counts = (int*)p;           p += (size_t)G * 4;
    int* maxd   = (int*)p;           p += 4;
    const size_t zero_bytes = (size_t)(NBKT_MAX + G + 1) * 4;
    (void)n_in; (void)ws_size;

    const int nbC = (E + 4095) / 4096;         // chunked edge blocks
    const int nbN = (N + 255) / 256;
    const int nbF = ((size_t)N * HIDDIM + 255) / 256;
    const int nbG = (N + 127) / 128;
    const int nbA = (N + 3) / 4;

    hipMemsetAsync(bcount, 0, zero_bytes, stream);

    // CSR build via bucketed counting sort
    k_bcount<<<nbC, 256, 0, stream>>>(edst, bcount, E);
    k_nodestats<<<nbN, 256, 0, stream>>>(batch, depth, counts, maxd, N, G);
    k_bscan<<<1, 512, 0, stream>>>(bcount, boff, bcur, rowptr, NBKT, N, E);
    k_bscatter<<<nbC, 256, 0, stream>>>(esrc, edst, bcur, ebuf, E, NBKT);
    k_build<<<NBKT, 256, 0, stream>>>(ebuf, boff, rowptr, invd, srcs, N);

    // node features (bf16)
    k_feat<<<nbF, 256, 0, stream>>>(nt, ih, flags, depth, embN, embI, maxd, x0, N);

    // layer 0
    k_gemm<0><<<nbG, 256, 0, stream>>>(x0, Wn0, K0, N, nullptr, nullptr, nullptr, bufY);
    k_agg<<<nbA, 256, 0, stream>>>((const uint32_t*)bufY, rowptr, srcs, invd, bufZ, N);
    k_gemm<1><<<nbG, 256, 0, stream>>>(x0, Ws0, K0, N, bs0, bn0, bufZ, bufX1);

    // layer 1
    k_gemm<0><<<nbG, 256, 0, stream>>>(bufX1, Wn1, HIDDIM, N, nullptr, nullptr, nullptr, bufY);
    k_agg<<<nbA, 256, 0, stream>>>((const uint32_t*)bufY, rowptr, srcs, invd, bufZ, N);
    k_gemm<1><<<nbG, 256, 0, stream>>>(bufX1, Ws1, HIDDIM, N, bs1, bn1, bufZ, bufY);

    // pool + heads
    k_scang<<<1, 512, 0, stream>>>(counts, gstart, G);
    k_pool<<<G, 128, 0, stream>>>(bufY, gstart, counts, gmat);
    k_head<<<G, 128, 0, stream>>>(gmat, Wr, br, Wc, bc, out, G);
}

// Round 5
// 474.456 us; speedup vs baseline: 2.1080x; 1.3000x over previous
//
#include <hip/hip_runtime.h>
#include <cstdint>
#include <cstddef>

#define HIDDIM 128
#define NGRAPH_MAX 512
#define LDSPAD 136   // 128 + 8 bf16 pad: row stride 272B (16B-aligned, bank-conflict-free frag reads)
#define NBKT_MAX 512 // coarse buckets of 256 nodes (dst>>8); N<=131072

using short8 = __attribute__((ext_vector_type(8))) short;
using f32x4  = __attribute__((ext_vector_type(4))) float;

__device__ __forceinline__ unsigned short f2bf(float x) {
    union { float f; uint32_t u; } v; v.f = x;
    uint32_t r = v.u + 0x7fffu + ((v.u >> 16) & 1u);   // RNE
    return (unsigned short)(r >> 16);
}
__device__ __forceinline__ float bf2f(unsigned short h) {
    union { uint32_t u; float f; } v; v.u = ((uint32_t)h) << 16;
    return v.f;
}
__device__ __forceinline__ float bflo(uint32_t u) { return __uint_as_float(u << 16); }
__device__ __forceinline__ float bfhi(uint32_t u) { return __uint_as_float(u & 0xffff0000u); }

// ---------------------------------------------------------------- bucket histogram (dst>>8), LDS-aggregated
__global__ void k_bcount(const int* __restrict__ dst, int* __restrict__ bcount, int E) {
    __shared__ int hist[NBKT_MAX];
    int t = threadIdx.x;
    hist[t] = 0; hist[t + 256] = 0;
    __syncthreads();
    int c0 = blockIdx.x * 4096;
    int ce = min(4096, E - c0);
    for (int i = t; i < ce; i += 256)
        atomicAdd(&hist[dst[c0 + i] >> 8], 1);
    __syncthreads();
    for (int b = t; b < NBKT_MAX; b += 256)
        if (hist[b]) atomicAdd(&bcount[b], hist[b]);
}

// ---------------------------------------------------------------- bucket offsets (single block, 512 thr)
__global__ void k_bscan(const int* __restrict__ bcount, int* __restrict__ boff,
                        int* __restrict__ bcur, int* __restrict__ rowptr,
                        int nbkt, int N, int E) {
    __shared__ int sd[512];
    int t = threadIdx.x;
    int v = (t < nbkt) ? bcount[t] : 0;
    sd[t] = v;
    __syncthreads();
    for (int off = 1; off < 512; off <<= 1) {
        int x = (t >= off) ? sd[t - off] : 0;
        __syncthreads();
        sd[t] += x;
        __syncthreads();
    }
    if (t < nbkt) { boff[t] = sd[t] - v; bcur[t] = sd[t] - v; }
    if (t == 0) { boff[nbkt] = E; rowptr[N] = E; }
}

// ---------------------------------------------------------------- bucket scatter: LDS-sort 4096-edge chunk,
// per-(block,bucket) global reservation, coalesced run writes (XCD-local lines)
__global__ void k_bscatter(const int* __restrict__ src, const int* __restrict__ dst,
                           int* __restrict__ bcur, int2* __restrict__ ebuf, int E, int nbkt) {
    __shared__ int2 stage[4096];        // 32 KB
    __shared__ int hist[NBKT_MAX];
    __shared__ int ofs[NBKT_MAX];
    __shared__ int cur[NBKT_MAX];
    __shared__ int gbase[NBKT_MAX];
    __shared__ int scanbuf[256];
    int t = threadIdx.x;
    int c0 = blockIdx.x * 4096;
    int ce = min(4096, E - c0);

    hist[t] = 0; hist[t + 256] = 0;
    __syncthreads();
    for (int i = t; i < ce; i += 256)
        atomicAdd(&hist[dst[c0 + i] >> 8], 1);
    __syncthreads();
    int h2a = hist[2 * t], h2b = hist[2 * t + 1];
    int ps = h2a + h2b;
    scanbuf[t] = ps;
    __syncthreads();
    for (int off = 1; off < 256; off <<= 1) {
        int x = (t >= off) ? scanbuf[t - off] : 0;
        __syncthreads();
        scanbuf[t] += x;
        __syncthreads();
    }
    int ex = scanbuf[t] - ps;
    ofs[2 * t] = ex;           cur[2 * t] = ex;
    ofs[2 * t + 1] = ex + h2a; cur[2 * t + 1] = ex + h2a;
    __syncthreads();
    for (int i = t; i < ce; i += 256) {
        int d = dst[c0 + i];
        int p = atomicAdd(&cur[d >> 8], 1);
        stage[p] = make_int2(src[c0 + i], d);
    }
    __syncthreads();
    for (int b = t; b < nbkt; b += 256) {
        int c = hist[b];
        gbase[b] = c ? atomicAdd(&bcur[b], c) : 0;
    }
    __syncthreads();
    for (int j = t; j < ce; j += 256) {
        int2 p = stage[j];
        int b = p.y >> 8;
        ebuf[gbase[b] + (j - ofs[b])] = p;
    }
}

// ---------------------------------------------------------------- per-bucket CSR build: deg, rowptr, invd, srcs
__global__ void k_build(const int2* __restrict__ ebuf, const int* __restrict__ boff,
                        int* __restrict__ rowptr, float* __restrict__ invd,
                        int* __restrict__ srcs, int N) {
    __shared__ int ldeg[256];
    __shared__ int lofs[256];
    __shared__ int lcur[256];
    int b = blockIdx.x, t = threadIdx.x;
    int n0 = b << 8;
    int s = boff[b], e = boff[b + 1];
    ldeg[t] = 0;
    __syncthreads();
    for (int i = s + t; i < e; i += 256)
        atomicAdd(&ldeg[ebuf[i].y & 255], 1);
    __syncthreads();
    int v = ldeg[t];
    lofs[t] = v;
    __syncthreads();
    for (int off = 1; off < 256; off <<= 1) {
        int x = (t >= off) ? lofs[t - off] : 0;
        __syncthreads();
        lofs[t] += x;
        __syncthreads();
    }
    int excl = lofs[t] - v;
    int node = n0 + t;
    if (node < N) {
        rowptr[node] = s + excl;
        invd[node] = 1.0f / (float)max(v, 1);
    }
    lcur[t] = excl;
    __syncthreads();
    for (int i = s + t; i < e; i += 256) {
        int2 p = ebuf[i];
        int slot = atomicAdd(&lcur[p.y & 255], 1);
        srcs[s + slot] = p.x;
    }
}

// ---------------------------------------------------------------- per-node stats: graph counts + max depth
__global__ void k_nodestats(const int* __restrict__ batch, const int* __restrict__ depth,
                            int* __restrict__ counts, int* __restrict__ maxd, int N, int G) {
    __shared__ int hist[NGRAPH_MAX];
    __shared__ int red[256];
    int t = threadIdx.x;
    for (int b = t; b < G; b += 256) hist[b] = 0;
    __syncthreads();
    int i = blockIdx.x * 256 + t;
    int d = 0;
    if (i < N) {
        atomicAdd(&hist[batch[i]], 1);
        d = depth[i];
    }
    red[t] = d;
    __syncthreads();
    for (int off = 128; off > 0; off >>= 1) {
        if (t < off) red[t] = max(red[t], red[t + off]);
        __syncthreads();
    }
    if (t == 0) atomicMax(maxd, red[0]);
    for (int b = t; b < G; b += 256)
        if (hist[b]) atomicAdd(&counts[b], hist[b]);
}

// ---------------------------------------------------------------- node features [N,128] bf16 (cols 102..127 = 0)
__global__ void k_feat(const int* __restrict__ nt, const int* __restrict__ ih,
                       const float* __restrict__ flags, const int* __restrict__ depth,
                       const float* __restrict__ embN, const float* __restrict__ embI,
                       const int* __restrict__ maxd, unsigned short* __restrict__ x0, int N) {
    int idx = blockIdx.x * 256 + threadIdx.x;
    int i = idx >> 7;
    int f = idx & 127;
    if (i >= N) return;
    float v;
    if (f < 64)       v = embN[nt[i] * 64 + f];
    else if (f < 96)  v = embI[ih[i] * 32 + (f - 64)];
    else if (f < 101) v = flags[i * 5 + (f - 96)];
    else if (f == 101) {
        float md = fmaxf((float)(*maxd), 1.0f);
        v = (float)depth[i] / md;
    } else v = 0.0f;
    x0[(size_t)i * HIDDIM + f] = f2bf(v);
}

// ---------------------------------------------------------------- weight pre-transpose: Wt[n][k] bf16, K zero-padded to 128
// mat 0..3 = Wn0, Ws0, Wn1, Ws1. grid 512 blocks x 128 thr (block = one n-column).
__global__ void k_wt(const float* __restrict__ Wn0, const float* __restrict__ Ws0,
                     const float* __restrict__ Wn1, const float* __restrict__ Ws1,
                     int K0, unsigned short* __restrict__ Wt) {
    int b = blockIdx.x;
    int mat = b >> 7, n = b & 127, t = threadIdx.x;   // t = k
    const float* W = (mat == 0) ? Wn0 : (mat == 1) ? Ws0 : (mat == 2) ? Wn1 : Ws1;
    int K = (mat < 2) ? K0 : HIDDIM;
    Wt[(size_t)mat * HIDDIM * HIDDIM + n * HIDDIM + t] =
        (t < K) ? f2bf(W[(size_t)t * HIDDIM + n]) : (unsigned short)0;
}

// ---------------------------------------------------------------- dual bf16 MFMA GEMM (K=128 fixed):
// Y[N,128] = X @ Wn ;  S[N,128] = X @ Ws + bias_s + bias_n   (all bf16 out, fp32 acc)
// 128x128 tile/block, 256 thr, LDS = As + Bn + Bs (3 x 34.8KB = 104.4KB -> 1 block/CU).
// All staging via uint4 (conflict-light); B pre-transposed in Wt so no f2bf/transpose here.
__global__ __launch_bounds__(256, 1) void k_gemm2(
    const unsigned short* __restrict__ X,
    const unsigned short* __restrict__ Wtn, const unsigned short* __restrict__ Wts,
    int N, const float* __restrict__ bias_s, const float* __restrict__ bias_n,
    unsigned short* __restrict__ Y, unsigned short* __restrict__ S) {
    __shared__ unsigned short As[128 * LDSPAD];
    __shared__ unsigned short Bn[128 * LDSPAD];
    __shared__ unsigned short Bs[128 * LDSPAD];
    int t = threadIdx.x;
    int rowBase = blockIdx.x << 7;

    #pragma unroll
    for (int it = 0; it < 8; it++) {
        int idx = t + it * 256;
        int r = idx >> 4, seg = idx & 15;
        int gr = rowBase + r;
        uint4 v = make_uint4(0u, 0u, 0u, 0u);
        if (gr < N) v = *(const uint4*)(X + (size_t)gr * HIDDIM + seg * 8);
        *(uint4*)&As[r * LDSPAD + seg * 8] = v;
    }
    #pragma unroll
    for (int it = 0; it < 8; it++) {
        int idx = t + it * 256;
        int n = idx >> 4, seg = idx & 15;
        *(uint4*)&Bn[n * LDSPAD + seg * 8] = *(const uint4*)(Wtn + n * HIDDIM + seg * 8);
        *(uint4*)&Bs[n * LDSPAD + seg * 8] = *(const uint4*)(Wts + n * HIDDIM + seg * 8);
    }
    __syncthreads();

    int lane = t & 63;
    int wv = t >> 6;
    int ml = lane & 15;
    int quad = lane >> 4;
    int m0 = wv * 32;

    f32x4 accY[2][8], accS[2][8];
    #pragma unroll
    for (int i = 0; i < 2; i++)
        #pragma unroll
        for (int j = 0; j < 8; j++) {
            accY[i][j] = (f32x4){0.f, 0.f, 0.f, 0.f};
            accS[i][j] = (f32x4){0.f, 0.f, 0.f, 0.f};
        }

    #pragma unroll
    for (int kt = 0; kt < 4; kt++) {
        int ko = kt * 32 + quad * 8;
        short8 a0 = *(const short8*)&As[(m0 + ml) * LDSPAD + ko];
        short8 a1 = *(const short8*)&As[(m0 + 16 + ml) * LDSPAD + ko];
        #pragma unroll
        for (int nt = 0; nt < 8; nt++) {
            short8 bn = *(const short8*)&Bn[(nt * 16 + ml) * LDSPAD + ko];
            accY[0][nt] = __builtin_amdgcn_mfma_f32_16x16x32_bf16(a0, bn, accY[0][nt], 0, 0, 0);
            accY[1][nt] = __builtin_amdgcn_mfma_f32_16x16x32_bf16(a1, bn, accY[1][nt], 0, 0, 0);
            short8 bs = *(const short8*)&Bs[(nt * 16 + ml) * LDSPAD + ko];
            accS[0][nt] = __builtin_amdgcn_mfma_f32_16x16x32_bf16(a0, bs, accS[0][nt], 0, 0, 0);
            accS[1][nt] = __builtin_amdgcn_mfma_f32_16x16x32_bf16(a1, bs, accS[1][nt], 0, 0, 0);
        }
    }

    float bsum[8];
    #pragma unroll
    for (int nt = 0; nt < 8; nt++) {
        int col = nt * 16 + ml;
        bsum[nt] = bias_s[col] + bias_n[col];
    }

    #pragma unroll
    for (int mt = 0; mt < 2; mt++) {
        int grow0 = rowBase + m0 + mt * 16 + quad * 4;
        #pragma unroll
        for (int r = 0; r < 4; r++) {
            int grow = grow0 + r;
            if (grow >= N) continue;
            #pragma unroll
            for (int nt = 0; nt < 8; nt++) {
                int col = nt * 16 + ml;
                Y[(size_t)grow * HIDDIM + col] = f2bf(accY[mt][nt][r]);
                S[(size_t)grow * HIDDIM + col] = f2bf(accS[mt][nt][r] + bsum[nt]);
            }
        }
    }
}

// ---------------------------------------------------------------- fused aggregate+combine: one WAVE per dst
// xo[d] = relu(s[d] + invd[d] * sum_{e in in(d)} y[src[e]]) ; all rows bf16 (uint32 = 2 cols/lane)
// gather unrolled x8 for memory-level parallelism (latency-bound per r4 counters)
__global__ void k_aggc(const uint32_t* __restrict__ y2, const uint32_t* __restrict__ s2,
                       const int* __restrict__ rp, const int* __restrict__ srcs,
                       const float* __restrict__ invd, uint32_t* __restrict__ xo, int N) {
    int lane = threadIdx.x & 63;
    int d = blockIdx.x * 4 + (threadIdx.x >> 6);
    if (d >= N) return;
    int s = rp[d], e = rp[d + 1];
    float a0 = 0.f, a1 = 0.f;
    for (int base = s; base < e; base += 64) {
        int m = min(64, e - base);
        int idx = (lane < m) ? srcs[base + lane] : 0;
        int j = 0;
        for (; j + 8 <= m; j += 8) {
            int i0 = __shfl(idx, j + 0, 64), i1 = __shfl(idx, j + 1, 64);
            int i2 = __shfl(idx, j + 2, 64), i3 = __shfl(idx, j + 3, 64);
            int i4 = __shfl(idx, j + 4, 64), i5 = __shfl(idx, j + 5, 64);
            int i6 = __shfl(idx, j + 6, 64), i7 = __shfl(idx, j + 7, 64);
            uint32_t u0 = y2[(size_t)i0 * 64 + lane];
            uint32_t u1 = y2[(size_t)i1 * 64 + lane];
            uint32_t u2 = y2[(size_t)i2 * 64 + lane];
            uint32_t u3 = y2[(size_t)i3 * 64 + lane];
            uint32_t u4 = y2[(size_t)i4 * 64 + lane];
            uint32_t u5 = y2[(size_t)i5 * 64 + lane];
            uint32_t u6 = y2[(size_t)i6 * 64 + lane];
            uint32_t u7 = y2[(size_t)i7 * 64 + lane];
            a0 += bflo(u0); a1 += bfhi(u0);
            a0 += bflo(u1); a1 += bfhi(u1);
            a0 += bflo(u2); a1 += bfhi(u2);
            a0 += bflo(u3); a1 += bfhi(u3);
            a0 += bflo(u4); a1 += bfhi(u4);
            a0 += bflo(u5); a1 += bfhi(u5);
            a0 += bflo(u6); a1 += bfhi(u6);
            a0 += bflo(u7); a1 += bfhi(u7);
        }
        for (; j < m; j++) {
            int id = __shfl(idx, j, 64);
            uint32_t u = y2[(size_t)id * 64 + lane];
            a0 += bflo(u); a1 += bfhi(u);
        }
    }
    float iv = invd[d];
    uint32_t su = s2[(size_t)d * 64 + lane];
    float o0 = fmaxf(bflo(su) + a0 * iv, 0.f);
    float o1 = fmaxf(bfhi(su) + a1 * iv, 0.f);
    xo[(size_t)d * 64 + lane] = (uint32_t)f2bf(o0) | ((uint32_t)f2bf(o1) << 16);
}

// ---------------------------------------------------------------- graph-start offsets (counts scan, G<=512)
__global__ void k_scang(const int* __restrict__ counts, int* __restrict__ gstart, int G) {
    __shared__ int sd[NGRAPH_MAX];
    int t = threadIdx.x;  // blockDim = 512
    int v = (t < G) ? counts[t] : 0;
    sd[t] = v;
    __syncthreads();
    for (int off = 1; off < 512; off <<= 1) {
        int x = (t >= off) ? sd[t - off] : 0;
        __syncthreads();
        sd[t] += x;
        __syncthreads();
    }
    if (t < G) gstart[t] = sd[t] - v;
    if (t == G - 1) gstart[G] = sd[t];
}

// ---------------------------------------------------------------- mean pool (sorted batch -> contiguous row ranges)
__global__ void k_pool(const unsigned short* __restrict__ x, const int* __restrict__ gstart,
                       const int* __restrict__ counts, float* __restrict__ g) {
    int gr = blockIdx.x;
    int t = threadIdx.x;
    int s = gstart[gr], e = gstart[gr + 1];
    float acc = 0.f;
    for (int i = s; i < e; i++)
        acc += bf2f(x[(size_t)i * HIDDIM + t]);
    g[(size_t)gr * HIDDIM + t] = acc / fmaxf((float)counts[gr], 1.f);
}

// ---------------------------------------------------------------- output heads
__global__ void k_head(const float* __restrict__ g, const float* __restrict__ Wr,
                       const float* __restrict__ br, const float* __restrict__ Wc,
                       const float* __restrict__ bc, float* __restrict__ out, int G) {
    __shared__ float row[128];
    int gr = blockIdx.x;
    int t = threadIdx.x;
    row[t] = g[(size_t)gr * HIDDIM + t];
    __syncthreads();
    if (t == 0) {
        float s = 0.f;
        for (int k = 0; k < 128; k++) s += row[k] * Wr[k];
        out[gr] = s + br[0];
    } else if (t <= 10) {
        int j = t - 1;
        float s = 0.f;
        for (int k = 0; k < 128; k++) s += row[k] * Wc[k * 10 + j];
        out[G + gr * 10 + j] = s + bc[j];
    }
}

// ================================================================ host
extern "C" void kernel_launch(void* const* d_in, const int* in_sizes, int n_in,
                              void* d_out, int out_size, void* d_ws, size_t ws_size,
                              hipStream_t stream) {
    const int*   nt    = (const int*)d_in[0];
    const int*   ih    = (const int*)d_in[1];
    const float* flags = (const float*)d_in[2];
    const int*   depth = (const int*)d_in[3];
    const int*   eidx  = (const int*)d_in[4];
    const int*   batch = (const int*)d_in[5];
    const float* embN  = (const float*)d_in[6];
    const float* embI  = (const float*)d_in[7];
    const float* Ws0   = (const float*)d_in[8];
    const float* bs0   = (const float*)d_in[9];
    const float* Wn0   = (const float*)d_in[10];
    const float* bn0   = (const float*)d_in[11];
    const float* Ws1   = (const float*)d_in[12];
    const float* bs1   = (const float*)d_in[13];
    const float* Wn1   = (const float*)d_in[14];
    const float* bn1   = (const float*)d_in[15];
    const float* Wr    = (const float*)d_in[16];
    const float* br    = (const float*)d_in[17];
    const float* Wc    = (const float*)d_in[18];
    const float* bc    = (const float*)d_in[19];
    float* out = (float*)d_out;

    const int N  = in_sizes[0];
    const int E  = in_sizes[4] / 2;
    const int K0 = in_sizes[8] / HIDDIM;   // 102
    const int G  = out_size / 11;          // 512
    const int* esrc = eidx;
    const int* edst = eidx + E;
    const int NBKT = (N + 255) >> 8;       // 391

    // ---- workspace carve-up (d_ws base is 16B-aligned; NH is a multiple of 16)
    char* w = (char*)d_ws;
    const size_t NH = (size_t)N * HIDDIM * sizeof(unsigned short);
    unsigned short* bufA = (unsigned short*)(w);            // x0, later x2
    unsigned short* bufY = (unsigned short*)(w + NH);       // y (both layers)
    unsigned short* bufS = (unsigned short*)(w + 2 * NH);   // s (both layers)
    unsigned short* bufX1= (unsigned short*)(w + 3 * NH);   // x1
    char* p = w + 4 * NH;
    unsigned short* Wt = (unsigned short*)p; p += (size_t)4 * HIDDIM * HIDDIM * 2;  // 128KB
    int2* ebuf  = (int2*)p;          p += (size_t)E * 8;
    int* srcs   = (int*)p;           p += (size_t)E * 4;
    int* rowptr = (int*)p;           p += (size_t)(N + 1) * 4;
    float* invd = (float*)p;         p += (size_t)N * 4;
    int* gstart = (int*)p;           p += (size_t)(G + 1) * 4;
    float* gmat = (float*)p;         p += (size_t)G * HIDDIM * 4;
    int* boff   = (int*)p;           p += (size_t)(NBKT_MAX + 1) * 4;
    int* bcur   = (int*)p;           p += (size_t)NBKT_MAX * 4;
    // zeroed block: bcount, counts, maxd (contiguous)
    int* bcount = (int*)p;           p += (size_t)NBKT_MAX * 4;
    int* counts = (int*)p;           p += (size_t)G * 4;
    int* maxd   = (int*)p;           p += 4;
    const size_t zero_bytes = (size_t)(NBKT_MAX + G + 1) * 4;
    (void)n_in; (void)ws_size;

    const int nbC = (E + 4095) / 4096;
    const int nbN = (N + 255) / 256;
    const int nbF = ((size_t)N * HIDDIM + 255) / 256;
    const int nbG = (N + 127) / 128;
    const int nbA = (N + 3) / 4;

    hipMemsetAsync(bcount, 0, zero_bytes, stream);

    // CSR build via bucketed counting sort
    k_bcount<<<nbC, 256, 0, stream>>>(edst, bcount, E);
    k_nodestats<<<nbN, 256, 0, stream>>>(batch, depth, counts, maxd, N, G);
    k_wt<<<512, 128, 0, stream>>>(Wn0, Ws0, Wn1, Ws1, K0, Wt);
    k_bscan<<<1, 512, 0, stream>>>(bcount, boff, bcur, rowptr, NBKT, N, E);
    k_bscatter<<<nbC, 256, 0, stream>>>(esrc, edst, bcur, ebuf, E, NBKT);
    k_build<<<NBKT, 256, 0, stream>>>(ebuf, boff, rowptr, invd, srcs, N);

    // node features (bf16)
    k_feat<<<nbF, 256, 0, stream>>>(nt, ih, flags, depth, embN, embI, maxd, bufA, N);

    const unsigned short* Wt_n0 = Wt;
    const unsigned short* Wt_s0 = Wt + 1 * HIDDIM * HIDDIM;
    const unsigned short* Wt_n1 = Wt + 2 * HIDDIM * HIDDIM;
    const unsigned short* Wt_s1 = Wt + 3 * HIDDIM * HIDDIM;

    // layer 0: {y, s} = dual-gemm(x0) ; x1 = relu(s + invd * A y)
    k_gemm2<<<nbG, 256, 0, stream>>>(bufA, Wt_n0, Wt_s0, N, bs0, bn0, bufY, bufS);
    k_aggc<<<nbA, 256, 0, stream>>>((const uint32_t*)bufY, (const uint32_t*)bufS,
                                    rowptr, srcs, invd, (uint32_t*)bufX1, N);

    // layer 1: {y, s} = dual-gemm(x1) ; x2 = relu(s + invd * A y)  (into bufA)
    k_gemm2<<<nbG, 256, 0, stream>>>(bufX1, Wt_n1, Wt_s1, N, bs1, bn1, bufY, bufS);
    k_aggc<<<nbA, 256, 0, stream>>>((const uint32_t*)bufY, (const uint32_t*)bufS,
                                    rowptr, srcs, invd, (uint32_t*)bufA, N);

    // pool + heads
    k_scang<<<1, 512, 0, stream>>>(counts, gstart, G);
    k_pool<<<G, 128, 0, stream>>>(bufA, gstart, counts, gmat);
    k_head<<<G, 128, 0, stream>>>(gmat, Wr, br, Wc, bc, out, G);
}

// Round 6
// 404.026 us; speedup vs baseline: 2.4755x; 1.1743x over previous
//
#include <hip/hip_runtime.h>
#include <cstdint>
#include <cstddef>

#define HIDDIM 128
#define NGRAPH_MAX 512
#define LDSPAD 136   // 128 + 8 bf16 pad: row stride 272B (16B-aligned, bank-conflict-free frag reads)
#define NBKT_MAX 512 // coarse buckets of 256 nodes (dst>>8); N<=131072

using short8 = __attribute__((ext_vector_type(8))) short;
using f32x4  = __attribute__((ext_vector_type(4))) float;

__device__ __forceinline__ unsigned short f2bf(float x) {
    union { float f; uint32_t u; } v; v.f = x;
    uint32_t r = v.u + 0x7fffu + ((v.u >> 16) & 1u);   // RNE
    return (unsigned short)(r >> 16);
}
__device__ __forceinline__ float bf2f(unsigned short h) {
    union { uint32_t u; float f; } v; v.u = ((uint32_t)h) << 16;
    return v.f;
}
__device__ __forceinline__ float bflo(uint32_t u) { return __uint_as_float(u << 16); }
__device__ __forceinline__ float bfhi(uint32_t u) { return __uint_as_float(u & 0xffff0000u); }

// ---------------------------------------------------------------- bucket histogram (dst>>8), LDS-aggregated
__global__ void k_bcount(const int* __restrict__ dst, int* __restrict__ bcount, int E) {
    __shared__ int hist[NBKT_MAX];
    int t = threadIdx.x;
    hist[t] = 0; hist[t + 256] = 0;
    __syncthreads();
    int c0 = blockIdx.x * 4096;
    int ce = min(4096, E - c0);
    for (int i = t; i < ce; i += 256)
        atomicAdd(&hist[dst[c0 + i] >> 8], 1);
    __syncthreads();
    for (int b = t; b < NBKT_MAX; b += 256)
        if (hist[b]) atomicAdd(&bcount[b], hist[b]);
}

// ---------------------------------------------------------------- bucket offsets (single block, 512 thr)
__global__ void k_bscan(const int* __restrict__ bcount, int* __restrict__ boff,
                        int* __restrict__ bcur, int* __restrict__ rowptr,
                        int nbkt, int N, int E) {
    __shared__ int sd[512];
    int t = threadIdx.x;
    int v = (t < nbkt) ? bcount[t] : 0;
    sd[t] = v;
    __syncthreads();
    for (int off = 1; off < 512; off <<= 1) {
        int x = (t >= off) ? sd[t - off] : 0;
        __syncthreads();
        sd[t] += x;
        __syncthreads();
    }
    if (t < nbkt) { boff[t] = sd[t] - v; bcur[t] = sd[t] - v; }
    if (t == 0) { boff[nbkt] = E; rowptr[N] = E; }
}

// ---------------------------------------------------------------- bucket scatter: LDS-sort 4096-edge chunk,
// per-(block,bucket) global reservation, coalesced run writes (XCD-local lines)
__global__ void k_bscatter(const int* __restrict__ src, const int* __restrict__ dst,
                           int* __restrict__ bcur, int2* __restrict__ ebuf, int E, int nbkt) {
    __shared__ int2 stage[4096];        // 32 KB
    __shared__ int hist[NBKT_MAX];
    __shared__ int ofs[NBKT_MAX];
    __shared__ int cur[NBKT_MAX];
    __shared__ int gbase[NBKT_MAX];
    __shared__ int scanbuf[256];
    int t = threadIdx.x;
    int c0 = blockIdx.x * 4096;
    int ce = min(4096, E - c0);

    hist[t] = 0; hist[t + 256] = 0;
    __syncthreads();
    for (int i = t; i < ce; i += 256)
        atomicAdd(&hist[dst[c0 + i] >> 8], 1);
    __syncthreads();
    int h2a = hist[2 * t], h2b = hist[2 * t + 1];
    int ps = h2a + h2b;
    scanbuf[t] = ps;
    __syncthreads();
    for (int off = 1; off < 256; off <<= 1) {
        int x = (t >= off) ? scanbuf[t - off] : 0;
        __syncthreads();
        scanbuf[t] += x;
        __syncthreads();
    }
    int ex = scanbuf[t] - ps;
    ofs[2 * t] = ex;           cur[2 * t] = ex;
    ofs[2 * t + 1] = ex + h2a; cur[2 * t + 1] = ex + h2a;
    __syncthreads();
    for (int i = t; i < ce; i += 256) {
        int d = dst[c0 + i];
        int p = atomicAdd(&cur[d >> 8], 1);
        stage[p] = make_int2(src[c0 + i], d);
    }
    __syncthreads();
    for (int b = t; b < nbkt; b += 256) {
        int c = hist[b];
        gbase[b] = c ? atomicAdd(&bcur[b], c) : 0;
    }
    __syncthreads();
    for (int j = t; j < ce; j += 256) {
        int2 p = stage[j];
        int b = p.y >> 8;
        ebuf[gbase[b] + (j - ofs[b])] = p;
    }
}

// ---------------------------------------------------------------- per-bucket CSR build: deg, rowptr, invd, srcs
__global__ void k_build(const int2* __restrict__ ebuf, const int* __restrict__ boff,
                        int* __restrict__ rowptr, float* __restrict__ invd,
                        int* __restrict__ srcs, int N) {
    __shared__ int ldeg[256];
    __shared__ int lofs[256];
    __shared__ int lcur[256];
    int b = blockIdx.x, t = threadIdx.x;
    int n0 = b << 8;
    int s = boff[b], e = boff[b + 1];
    ldeg[t] = 0;
    __syncthreads();
    for (int i = s + t; i < e; i += 256)
        atomicAdd(&ldeg[ebuf[i].y & 255], 1);
    __syncthreads();
    int v = ldeg[t];
    lofs[t] = v;
    __syncthreads();
    for (int off = 1; off < 256; off <<= 1) {
        int x = (t >= off) ? lofs[t - off] : 0;
        __syncthreads();
        lofs[t] += x;
        __syncthreads();
    }
    int excl = lofs[t] - v;
    int node = n0 + t;
    if (node < N) {
        rowptr[node] = s + excl;
        invd[node] = 1.0f / (float)max(v, 1);
    }
    lcur[t] = excl;
    __syncthreads();
    for (int i = s + t; i < e; i += 256) {
        int2 p = ebuf[i];
        int slot = atomicAdd(&lcur[p.y & 255], 1);
        srcs[s + slot] = p.x;
    }
}

// ---------------------------------------------------------------- per-node stats: graph counts + max depth
__global__ void k_nodestats(const int* __restrict__ batch, const int* __restrict__ depth,
                            int* __restrict__ counts, int* __restrict__ maxd, int N, int G) {
    __shared__ int hist[NGRAPH_MAX];
    __shared__ int red[256];
    int t = threadIdx.x;
    for (int b = t; b < G; b += 256) hist[b] = 0;
    __syncthreads();
    int i = blockIdx.x * 256 + t;
    int d = 0;
    if (i < N) {
        atomicAdd(&hist[batch[i]], 1);
        d = depth[i];
    }
    red[t] = d;
    __syncthreads();
    for (int off = 128; off > 0; off >>= 1) {
        if (t < off) red[t] = max(red[t], red[t + off]);
        __syncthreads();
    }
    if (t == 0) atomicMax(maxd, red[0]);
    for (int b = t; b < G; b += 256)
        if (hist[b]) atomicAdd(&counts[b], hist[b]);
}

// ---------------------------------------------------------------- node features [N,128] bf16 (cols 102..127 = 0)
__global__ void k_feat(const int* __restrict__ nt, const int* __restrict__ ih,
                       const float* __restrict__ flags, const int* __restrict__ depth,
                       const float* __restrict__ embN, const float* __restrict__ embI,
                       const int* __restrict__ maxd, unsigned short* __restrict__ x0, int N) {
    int idx = blockIdx.x * 256 + threadIdx.x;
    int i = idx >> 7;
    int f = idx & 127;
    if (i >= N) return;
    float v;
    if (f < 64)       v = embN[nt[i] * 64 + f];
    else if (f < 96)  v = embI[ih[i] * 32 + (f - 64)];
    else if (f < 101) v = flags[i * 5 + (f - 96)];
    else if (f == 101) {
        float md = fmaxf((float)(*maxd), 1.0f);
        v = (float)depth[i] / md;
    } else v = 0.0f;
    x0[(size_t)i * HIDDIM + f] = f2bf(v);
}

// ---------------------------------------------------------------- weight pre-transpose: Wt[n][k] bf16, K zero-padded to 128
__global__ void k_wt(const float* __restrict__ Wn0, const float* __restrict__ Ws0,
                     const float* __restrict__ Wn1, const float* __restrict__ Ws1,
                     int K0, unsigned short* __restrict__ Wt) {
    int b = blockIdx.x;
    int mat = b >> 7, n = b & 127, t = threadIdx.x;   // t = k
    const float* W = (mat == 0) ? Wn0 : (mat == 1) ? Ws0 : (mat == 2) ? Wn1 : Ws1;
    int K = (mat < 2) ? K0 : HIDDIM;
    Wt[(size_t)mat * HIDDIM * HIDDIM + n * HIDDIM + t] =
        (t < K) ? f2bf(W[(size_t)t * HIDDIM + n]) : (unsigned short)0;
}

// ---------------------------------------------------------------- dual bf16 MFMA GEMM (K=128 fixed):
// Y[N,128] = X @ Wn ;  S[N,128] = X @ Ws + bias_s + bias_n   (all bf16 out, fp32 acc)
__global__ __launch_bounds__(256, 1) void k_gemm2(
    const unsigned short* __restrict__ X,
    const unsigned short* __restrict__ Wtn, const unsigned short* __restrict__ Wts,
    int N, const float* __restrict__ bias_s, const float* __restrict__ bias_n,
    unsigned short* __restrict__ Y, unsigned short* __restrict__ S) {
    __shared__ unsigned short As[128 * LDSPAD];
    __shared__ unsigned short Bn[128 * LDSPAD];
    __shared__ unsigned short Bs[128 * LDSPAD];
    int t = threadIdx.x;
    int rowBase = blockIdx.x << 7;

    #pragma unroll
    for (int it = 0; it < 8; it++) {
        int idx = t + it * 256;
        int r = idx >> 4, seg = idx & 15;
        int gr = rowBase + r;
        uint4 v = make_uint4(0u, 0u, 0u, 0u);
        if (gr < N) v = *(const uint4*)(X + (size_t)gr * HIDDIM + seg * 8);
        *(uint4*)&As[r * LDSPAD + seg * 8] = v;
    }
    #pragma unroll
    for (int it = 0; it < 8; it++) {
        int idx = t + it * 256;
        int n = idx >> 4, seg = idx & 15;
        *(uint4*)&Bn[n * LDSPAD + seg * 8] = *(const uint4*)(Wtn + n * HIDDIM + seg * 8);
        *(uint4*)&Bs[n * LDSPAD + seg * 8] = *(const uint4*)(Wts + n * HIDDIM + seg * 8);
    }
    __syncthreads();

    int lane = t & 63;
    int wv = t >> 6;
    int ml = lane & 15;
    int quad = lane >> 4;
    int m0 = wv * 32;

    f32x4 accY[2][8], accS[2][8];
    #pragma unroll
    for (int i = 0; i < 2; i++)
        #pragma unroll
        for (int j = 0; j < 8; j++) {
            accY[i][j] = (f32x4){0.f, 0.f, 0.f, 0.f};
            accS[i][j] = (f32x4){0.f, 0.f, 0.f, 0.f};
        }

    #pragma unroll
    for (int kt = 0; kt < 4; kt++) {
        int ko = kt * 32 + quad * 8;
        short8 a0 = *(const short8*)&As[(m0 + ml) * LDSPAD + ko];
        short8 a1 = *(const short8*)&As[(m0 + 16 + ml) * LDSPAD + ko];
        #pragma unroll
        for (int nt = 0; nt < 8; nt++) {
            short8 bn = *(const short8*)&Bn[(nt * 16 + ml) * LDSPAD + ko];
            accY[0][nt] = __builtin_amdgcn_mfma_f32_16x16x32_bf16(a0, bn, accY[0][nt], 0, 0, 0);
            accY[1][nt] = __builtin_amdgcn_mfma_f32_16x16x32_bf16(a1, bn, accY[1][nt], 0, 0, 0);
            short8 bs = *(const short8*)&Bs[(nt * 16 + ml) * LDSPAD + ko];
            accS[0][nt] = __builtin_amdgcn_mfma_f32_16x16x32_bf16(a0, bs, accS[0][nt], 0, 0, 0);
            accS[1][nt] = __builtin_amdgcn_mfma_f32_16x16x32_bf16(a1, bs, accS[1][nt], 0, 0, 0);
        }
    }

    float bsum[8];
    #pragma unroll
    for (int nt = 0; nt < 8; nt++) {
        int col = nt * 16 + ml;
        bsum[nt] = bias_s[col] + bias_n[col];
    }

    #pragma unroll
    for (int mt = 0; mt < 2; mt++) {
        int grow0 = rowBase + m0 + mt * 16 + quad * 4;
        #pragma unroll
        for (int r = 0; r < 4; r++) {
            int grow = grow0 + r;
            if (grow >= N) continue;
            #pragma unroll
            for (int nt = 0; nt < 8; nt++) {
                int col = nt * 16 + ml;
                Y[(size_t)grow * HIDDIM + col] = f2bf(accY[mt][nt][r]);
                S[(size_t)grow * HIDDIM + col] = f2bf(accS[mt][nt][r] + bsum[nt]);
            }
        }
    }
}

// ---------------------------------------------------------------- fused aggregate+combine: one WAVE per dst,
// HALF-WAVE per edge (even/odd pairing): lane = (half = edge parity, cl = uint2 col-group).
// One 8B load per lane fetches TWO rows per step across the wave -> 2x bytes/request vs r5.
// xo[d] = relu(s[d] + invd[d] * sum y[src[e]])
__global__ void k_aggc(const uint32_t* __restrict__ y, const uint32_t* __restrict__ s2,
                       const int* __restrict__ rp, const int* __restrict__ srcs,
                       const float* __restrict__ invd, uint32_t* __restrict__ xo, int N) {
    int t = threadIdx.x;
    int lane = t & 63;
    int half = lane >> 5;          // 0: even edge of pair, 1: odd edge
    int cl = lane & 31;            // uint2 index within row (cols 4cl..4cl+3)
    int d = blockIdx.x * 4 + (t >> 6);
    if (d >= N) return;
    int s = rp[d], e = rp[d + 1];
    const uint2* y2 = (const uint2*)y;
    float a0 = 0.f, a1 = 0.f, a2 = 0.f, a3 = 0.f;
    for (int base = s; base < e; base += 64) {
        int m = min(64, e - base);
        int idx = (lane < m) ? srcs[base + lane] : 0;
        int j = 0;
        for (; j + 8 <= m; j += 8) {           // 8 edges = 4 pair-steps in flight
            int i0 = __shfl(idx, j + 0 + half, 64);
            int i1 = __shfl(idx, j + 2 + half, 64);
            int i2 = __shfl(idx, j + 4 + half, 64);
            int i3 = __shfl(idx, j + 6 + half, 64);
            uint2 u0 = y2[(size_t)i0 * 32 + cl];
            uint2 u1 = y2[(size_t)i1 * 32 + cl];
            uint2 u2 = y2[(size_t)i2 * 32 + cl];
            uint2 u3 = y2[(size_t)i3 * 32 + cl];
            a0 += bflo(u0.x); a1 += bfhi(u0.x); a2 += bflo(u0.y); a3 += bfhi(u0.y);
            a0 += bflo(u1.x); a1 += bfhi(u1.x); a2 += bflo(u1.y); a3 += bfhi(u1.y);
            a0 += bflo(u2.x); a1 += bfhi(u2.x); a2 += bflo(u2.y); a3 += bfhi(u2.y);
            a0 += bflo(u3.x); a1 += bfhi(u3.x); a2 += bflo(u3.y); a3 += bfhi(u3.y);
        }
        for (; j + 2 <= m; j += 2) {
            int id = __shfl(idx, j + half, 64);
            uint2 u = y2[(size_t)id * 32 + cl];
            a0 += bflo(u.x); a1 += bfhi(u.x); a2 += bflo(u.y); a3 += bfhi(u.y);
        }
        if (j < m) {                           // odd leftover edge: half 0 only
            int id = __shfl(idx, j, 64);
            if (half == 0) {
                uint2 u = y2[(size_t)id * 32 + cl];
                a0 += bflo(u.x); a1 += bfhi(u.x); a2 += bflo(u.y); a3 += bfhi(u.y);
            }
        }
    }
    // combine even/odd halves (lanes 0-31 <- +lane+32)
    a0 += __shfl_down(a0, 32, 64);
    a1 += __shfl_down(a1, 32, 64);
    a2 += __shfl_down(a2, 32, 64);
    a3 += __shfl_down(a3, 32, 64);
    if (half == 0) {
        float iv = invd[d];
        uint2 su = ((const uint2*)s2)[(size_t)d * 32 + cl];
        float o0 = fmaxf(bflo(su.x) + a0 * iv, 0.f);
        float o1 = fmaxf(bfhi(su.x) + a1 * iv, 0.f);
        float o2 = fmaxf(bflo(su.y) + a2 * iv, 0.f);
        float o3 = fmaxf(bfhi(su.y) + a3 * iv, 0.f);
        uint2 o;
        o.x = (uint32_t)f2bf(o0) | ((uint32_t)f2bf(o1) << 16);
        o.y = (uint32_t)f2bf(o2) | ((uint32_t)f2bf(o3) << 16);
        ((uint2*)xo)[(size_t)d * 32 + cl] = o;
    }
}

// ---------------------------------------------------------------- graph-start offsets (counts scan, G<=512)
__global__ void k_scang(const int* __restrict__ counts, int* __restrict__ gstart, int G) {
    __shared__ int sd[NGRAPH_MAX];
    int t = threadIdx.x;  // blockDim = 512
    int v = (t < G) ? counts[t] : 0;
    sd[t] = v;
    __syncthreads();
    for (int off = 1; off < 512; off <<= 1) {
        int x = (t >= off) ? sd[t - off] : 0;
        __syncthreads();
        sd[t] += x;
        __syncthreads();
    }
    if (t < G) gstart[t] = sd[t] - v;
    if (t == G - 1) gstart[G] = sd[t];
}

// ---------------------------------------------------------------- mean pool v2: 256 thr/graph, uint2 lanes,
// 2 rows/wave-step, 4-deep unroll (32 rows in flight/block), shfl+LDS reduce, float4 store
__global__ void k_pool(const uint32_t* __restrict__ x, const int* __restrict__ gstart,
                       const int* __restrict__ counts, float* __restrict__ g) {
    __shared__ float red[3][128];
    int gr = blockIdx.x, t = threadIdx.x;
    int wv = t >> 6, lane = t & 63;
    int half = lane >> 5, cl = lane & 31;
    int s = gstart[gr], e = gstart[gr + 1];
    const uint2* x2 = (const uint2*)x;
    float a0 = 0.f, a1 = 0.f, a2 = 0.f, a3 = 0.f;
    for (int r0 = s + wv * 2 + half; r0 < e; r0 += 32) {
        uint2 u0 = x2[(size_t)r0 * 32 + cl];
        int r1 = r0 + 8, r2 = r0 + 16, r3 = r0 + 24;
        uint2 u1 = make_uint2(0u, 0u), u2 = make_uint2(0u, 0u), u3 = make_uint2(0u, 0u);
        if (r1 < e) u1 = x2[(size_t)r1 * 32 + cl];
        if (r2 < e) u2 = x2[(size_t)r2 * 32 + cl];
        if (r3 < e) u3 = x2[(size_t)r3 * 32 + cl];
        a0 += bflo(u0.x); a1 += bfhi(u0.x); a2 += bflo(u0.y); a3 += bfhi(u0.y);
        a0 += bflo(u1.x); a1 += bfhi(u1.x); a2 += bflo(u1.y); a3 += bfhi(u1.y);
        a0 += bflo(u2.x); a1 += bfhi(u2.x); a2 += bflo(u2.y); a3 += bfhi(u2.y);
        a0 += bflo(u3.x); a1 += bfhi(u3.x); a2 += bflo(u3.y); a3 += bfhi(u3.y);
    }
    a0 += __shfl_down(a0, 32, 64);
    a1 += __shfl_down(a1, 32, 64);
    a2 += __shfl_down(a2, 32, 64);
    a3 += __shfl_down(a3, 32, 64);
    if (half == 0 && wv > 0) {
        red[wv - 1][cl * 4 + 0] = a0;
        red[wv - 1][cl * 4 + 1] = a1;
        red[wv - 1][cl * 4 + 2] = a2;
        red[wv - 1][cl * 4 + 3] = a3;
    }
    __syncthreads();
    if (wv == 0 && half == 0) {
        a0 += red[0][cl * 4 + 0] + red[1][cl * 4 + 0] + red[2][cl * 4 + 0];
        a1 += red[0][cl * 4 + 1] + red[1][cl * 4 + 1] + red[2][cl * 4 + 1];
        a2 += red[0][cl * 4 + 2] + red[1][cl * 4 + 2] + red[2][cl * 4 + 2];
        a3 += red[0][cl * 4 + 3] + red[1][cl * 4 + 3] + red[2][cl * 4 + 3];
        float inv = 1.0f / fmaxf((float)counts[gr], 1.0f);
        float4 o = make_float4(a0 * inv, a1 * inv, a2 * inv, a3 * inv);
        *(float4*)&g[(size_t)gr * HIDDIM + cl * 4] = o;
    }
}

// ---------------------------------------------------------------- output heads
__global__ void k_head(const float* __restrict__ g, const float* __restrict__ Wr,
                       const float* __restrict__ br, const float* __restrict__ Wc,
                       const float* __restrict__ bc, float* __restrict__ out, int G) {
    __shared__ float row[128];
    int gr = blockIdx.x;
    int t = threadIdx.x;
    row[t] = g[(size_t)gr * HIDDIM + t];
    __syncthreads();
    if (t == 0) {
        float s = 0.f;
        for (int k = 0; k < 128; k++) s += row[k] * Wr[k];
        out[gr] = s + br[0];
    } else if (t <= 10) {
        int j = t - 1;
        float s = 0.f;
        for (int k = 0; k < 128; k++) s += row[k] * Wc[k * 10 + j];
        out[G + gr * 10 + j] = s + bc[j];
    }
}

// ================================================================ host
extern "C" void kernel_launch(void* const* d_in, const int* in_sizes, int n_in,
                              void* d_out, int out_size, void* d_ws, size_t ws_size,
                              hipStream_t stream) {
    const int*   nt    = (const int*)d_in[0];
    const int*   ih    = (const int*)d_in[1];
    const float* flags = (const float*)d_in[2];
    const int*   depth = (const int*)d_in[3];
    const int*   eidx  = (const int*)d_in[4];
    const int*   batch = (const int*)d_in[5];
    const float* embN  = (const float*)d_in[6];
    const float* embI  = (const float*)d_in[7];
    const float* Ws0   = (const float*)d_in[8];
    const float* bs0   = (const float*)d_in[9];
    const float* Wn0   = (const float*)d_in[10];
    const float* bn0   = (const float*)d_in[11];
    const float* Ws1   = (const float*)d_in[12];
    const float* bs1   = (const float*)d_in[13];
    const float* Wn1   = (const float*)d_in[14];
    const float* bn1   = (const float*)d_in[15];
    const float* Wr    = (const float*)d_in[16];
    const float* br    = (const float*)d_in[17];
    const float* Wc    = (const float*)d_in[18];
    const float* bc    = (const float*)d_in[19];
    float* out = (float*)d_out;

    const int N  = in_sizes[0];
    const int E  = in_sizes[4] / 2;
    const int K0 = in_sizes[8] / HIDDIM;   // 102
    const int G  = out_size / 11;          // 512
    const int* esrc = eidx;
    const int* edst = eidx + E;
    const int NBKT = (N + 255) >> 8;       // 391

    // ---- workspace carve-up (d_ws base is 16B-aligned; NH is a multiple of 16)
    char* w = (char*)d_ws;
    const size_t NH = (size_t)N * HIDDIM * sizeof(unsigned short);
    unsigned short* bufA = (unsigned short*)(w);            // x0, later x2
    unsigned short* bufY = (unsigned short*)(w + NH);       // y (both layers)
    unsigned short* bufS = (unsigned short*)(w + 2 * NH);   // s (both layers)
    unsigned short* bufX1= (unsigned short*)(w + 3 * NH);   // x1
    char* p = w + 4 * NH;
    unsigned short* Wt = (unsigned short*)p; p += (size_t)4 * HIDDIM * HIDDIM * 2;  // 128KB
    int2* ebuf  = (int2*)p;          p += (size_t)E * 8;
    int* srcs   = (int*)p;           p += (size_t)E * 4;
    int* rowptr = (int*)p;           p += (size_t)(N + 1) * 4;
    float* invd = (float*)p;         p += (size_t)N * 4;
    int* gstart = (int*)p;           p += (size_t)(G + 1) * 4;
    float* gmat = (float*)p;         p += (size_t)G * HIDDIM * 4;
    int* boff   = (int*)p;           p += (size_t)(NBKT_MAX + 1) * 4;
    int* bcur   = (int*)p;           p += (size_t)NBKT_MAX * 4;
    // zeroed block: bcount, counts, maxd (contiguous)
    int* bcount = (int*)p;           p += (size_t)NBKT_MAX * 4;
    int* counts = (int*)p;           p += (size_t)G * 4;
    int* maxd   = (int*)p;           p += 4;
    const size_t zero_bytes = (size_t)(NBKT_MAX + G + 1) * 4;
    (void)n_in; (void)ws_size;

    const int nbC = (E + 4095) / 4096;
    const int nbN = (N + 255) / 256;
    const int nbF = ((size_t)N * HIDDIM + 255) / 256;
    const int nbG = (N + 127) / 128;
    const int nbA = (N + 3) / 4;

    hipMemsetAsync(bcount, 0, zero_bytes, stream);

    // CSR build via bucketed counting sort
    k_bcount<<<nbC, 256, 0, stream>>>(edst, bcount, E);
    k_nodestats<<<nbN, 256, 0, stream>>>(batch, depth, counts, maxd, N, G);
    k_wt<<<512, 128, 0, stream>>>(Wn0, Ws0, Wn1, Ws1, K0, Wt);
    k_bscan<<<1, 512, 0, stream>>>(bcount, boff, bcur, rowptr, NBKT, N, E);
    k_bscatter<<<nbC, 256, 0, stream>>>(esrc, edst, bcur, ebuf, E, NBKT);
    k_build<<<NBKT, 256, 0, stream>>>(ebuf, boff, rowptr, invd, srcs, N);

    // node features (bf16)
    k_feat<<<nbF, 256, 0, stream>>>(nt, ih, flags, depth, embN, embI, maxd, bufA, N);

    const unsigned short* Wt_n0 = Wt;
    const unsigned short* Wt_s0 = Wt + 1 * HIDDIM * HIDDIM;
    const unsigned short* Wt_n1 = Wt + 2 * HIDDIM * HIDDIM;
    const unsigned short* Wt_s1 = Wt + 3 * HIDDIM * HIDDIM;

    // layer 0: {y, s} = dual-gemm(x0) ; x1 = relu(s + invd * A y)
    k_gemm2<<<nbG, 256, 0, stream>>>(bufA, Wt_n0, Wt_s0, N, bs0, bn0, bufY, bufS);
    k_aggc<<<nbA, 256, 0, stream>>>((const uint32_t*)bufY, (const uint32_t*)bufS,
                                    rowptr, srcs, invd, (uint32_t*)bufX1, N);

    // layer 1: {y, s} = dual-gemm(x1) ; x2 = relu(s + invd * A y)  (into bufA)
    k_gemm2<<<nbG, 256, 0, stream>>>(bufX1, Wt_n1, Wt_s1, N, bs1, bn1, bufY, bufS);
    k_aggc<<<nbA, 256, 0, stream>>>((const uint32_t*)bufY, (const uint32_t*)bufS,
                                    rowptr, srcs, invd, (uint32_t*)bufA, N);

    // pool + heads
    k_scang<<<1, 512, 0, stream>>>(counts, gstart, G);
    k_pool<<<G, 256, 0, stream>>>((const uint32_t*)bufA, gstart, counts, gmat);
    k_head<<<G, 128, 0, stream>>>(gmat, Wr, br, Wc, bc, out, G);
}